// Round 1
// baseline (202.384 us; speedup 1.0000x reference)
//
#include <hip/hip_runtime.h>
#include <stdint.h>

// FP32 in/out. bf16 only for MFMA operands (numeric path unchanged vs R8 kernel).
// R14 restructure: k_fused (40.2us, MfmaUtil 2.8%, latency-bound: 1 block/CU,
// 15 barrier phases, 256x redundant weight reload, per-block stats re-reduce)
// split into k_stats (once) + k_qkv (dense MFMA GEMM, 576 blocks, 1 barrier)
// + k_attn (8 heads parallel across 8 waves, 3 barriers, no weight traffic).
// Prior ledger: R6 mega-kernel +150us; R8 union prefetch spills +75us; R10
// launch_bounds spill +115us; R11 4-block split +90us; R12 fused softmax
// spill +45us; R13 finisher/memset +5us.

#define N_NODES 6144
#define GSIZE 24
#define NGRAPH 256
#define DIN 128
#define DH 64
#define EFF 512
#define EPSN 1e-5f

typedef __attribute__((ext_vector_type(8))) __bf16 bf16x8;
typedef __attribute__((ext_vector_type(4))) float f32x4;
union U16B { uint4 u; bf16x8 v; unsigned short s[8]; };

__device__ inline float bf2f(unsigned short u){ return __uint_as_float(((unsigned)u)<<16); }
__device__ inline unsigned short f2bf(float f){
  unsigned u = __float_as_uint(f);
  u += 0x7fff + ((u>>16)&1);
  return (unsigned short)(u>>16);
}
__device__ inline float gelu_exact(float x){ return 0.5f*x*(1.0f+erff(x*0.70710678118654752f)); }

// ---- workspace float offsets ----
#define XP    0         // 192 x 256 floats: x col sum/sumsq partials
#define HP    49152     // 256 x 128 floats: h col stat partials
#define WT1   81920
#define WT2   86016
#define PWT1  90112
#define FBo   94208     // 257 floats
#define AC    94720     // 128 floats A1 (scale) + 128 floats C1 (shift)
#define WCVT_BYTE  385024   // 3 x 512 x 128 bf16 = 393216 B
#define HCOMB_BYTE 778240   // 6144 x 64 fp32 -> ends 2351104
#define QKV_BYTE   2359296  // 6144 x 1536 fp32 = 37.75 MB

// ================= K1: k_pre =================
// blocks 0..191: x col-stat partials (32 rows each)
// blocks 192..194: transpose o_w1/o_w2/p_w1 (+bias staging in 192)
// blocks 195..206: wq/wk/wv -> bf16 (12 segments)
__global__ __launch_bounds__(256)
void k_pre(const float* __restrict__ x,
           const float* __restrict__ o_w1, const float* __restrict__ o_w2,
           const float* __restrict__ p_w1,
           const float* __restrict__ o_b1, const float* __restrict__ o_b2,
           const float* __restrict__ p_b1, const float* __restrict__ p_w2,
           const float* __restrict__ p_b2,
           const float* __restrict__ wq, const float* __restrict__ wk,
           const float* __restrict__ wv,
           float* __restrict__ wsf){
  int t = threadIdx.x;
  int bi = blockIdx.x;
  if(bi < 192){
    int c = t & 127, h = t >> 7;
    float s = 0.f, q = 0.f;
    #pragma unroll
    for(int r = 0; r < 16; ++r){
      float v = x[(size_t)(bi*32 + h + 2*r)*DIN + c];
      s += v; q += v*v;
    }
    __shared__ float sm[256], sm2[256];
    sm[t] = s; sm2[t] = q;
    __syncthreads();
    if(t < 128){
      wsf[XP + bi*256 + t]       = sm[t] + sm[t+128];
      wsf[XP + bi*256 + 128 + t] = sm2[t] + sm2[t+128];
    }
    return;
  }
  if(bi < 195){
    const float* src; float* dst;
    if(bi == 192){ src = o_w1; dst = wsf + WT1; }
    else if(bi == 193){ src = o_w2; dst = wsf + WT2; }
    else { src = p_w1; dst = wsf + PWT1; }
    for(int p = t; p < DH*DH; p += 256){
      int r = p >> 6, c = p & 63;
      dst[c*DH + r] = src[p];
    }
    if(bi == 192){
      float* fb = wsf + FBo;
      if(t < 64){
        fb[t]       = o_b1[t];
        fb[64 + t]  = o_b2[t];
        fb[128 + t] = p_b1[t];
        fb[192 + t] = p_w2[t];
      }
      if(t == 0) fb[256] = p_b2[0];
    }
    return;
  }
  int j = bi - 195;               // 0..11
  int mat = j >> 2, seg = j & 3;
  const float* src = (mat==0) ? wq : (mat==1) ? wk : wv;
  unsigned short* dst = (unsigned short*)((char*)wsf + WCVT_BYTE)
                        + (size_t)mat*EFF*DIN + seg*16384;
  const float* sp = src + seg*16384;
  for(int e = t*8; e < 16384; e += 2048){
    float4 a = *(const float4*)(sp + e);
    float4 b = *(const float4*)(sp + e + 4);
    U16B o;
    o.s[0]=f2bf(a.x); o.s[1]=f2bf(a.y); o.s[2]=f2bf(a.z); o.s[3]=f2bf(a.w);
    o.s[4]=f2bf(b.x); o.s[5]=f2bf(b.y); o.s[6]=f2bf(b.z); o.s[7]=f2bf(b.w);
    *(uint4*)(dst + e) = o.u;
  }
}

// ================= K1.5: k_stats =================
// Reduce XP partials -> A1 (scale) / C1 (shift) once, instead of per-block.
__global__ __launch_bounds__(512)
void k_stats(const float* __restrict__ nq_w, const float* __restrict__ nq_b,
             const float* __restrict__ nq_ms, float* __restrict__ ws){
  __shared__ float redA[512], redB[512];
  int t = threadIdx.x;
  int c = t & 127, grp = t >> 7;
  float s = 0.f, q = 0.f;
  for(int p = grp*48; p < grp*48 + 48; ++p){
    s += ws[XP + p*256 + c];
    q += ws[XP + p*256 + 128 + c];
  }
  redA[t] = s; redB[t] = q;
  __syncthreads();
  if(t < 128){
    float s1 = redA[t] + redA[t+128] + redA[t+256] + redA[t+384];
    float q1 = redB[t] + redB[t+128] + redB[t+256] + redB[t+384];
    float mean = s1 * (1.0f / N_NODES);
    float ex2  = q1 * (1.0f / N_NODES);
    float cm   = mean * nq_ms[t];
    float var  = ex2 - 2.f*cm*mean + cm*cm;
    float rstd = rsqrtf(var + EPSN);
    float a    = nq_w[t] * rstd;
    ws[AC + t]       = a;
    ws[AC + 128 + t] = nq_b[t] - a*cm;
  }
}

// ================= K2: k_qkv =================
// Dense GEMM: out[6144][1536] = norm(x)[6144][128] @ Wqkv^T, +bias, fp32 out.
// grid = 48 M-tiles x 12 N-tiles = 576 blocks (2/CU), 256 thr (4 waves),
// BM=BN=128, full K=128 in one staged shot, single barrier.
// LDS tiles XOR-swizzled ((row&7)<<4 on byte addr) -> conflict-free ds_read_b128.
__global__ __launch_bounds__(256)
void k_qkv(const float* __restrict__ x,
           const float* __restrict__ bq, const float* __restrict__ bk,
           const float* __restrict__ bv,
           const float* __restrict__ ws, float* __restrict__ qkv){
  __shared__ __align__(16) char lds[65536];
  char* Alds = lds;            // x-hat bf16 [128][128]
  char* Blds = lds + 32768;    // W bf16 [128][128]
  int t = threadIdx.x;
  int mt = blockIdx.x / 12, nt = blockIdx.x % 12;
  int mat = nt >> 2, obase = (nt & 3) * 128;
  const float* A1c = ws + AC;
  const unsigned short* wsrc = (const unsigned short*)((const char*)ws + WCVT_BYTE)
                               + (size_t)mat*EFF*DIN + (size_t)obase*DIN;
  // ---- stage A: load x rows, normalize per-column, cvt bf16, swizzled write
  {
    int kf = (t & 31) * 4;                       // f32 col index, fixed per thread
    float4 a4 = *(const float4*)(A1c + kf);
    float4 c4 = *(const float4*)(A1c + 128 + kf);
    #pragma unroll
    for(int it = 0; it < 16; ++it){
      int row = it*8 + (t >> 5);
      float4 v = *(const float4*)(x + (size_t)(mt*128 + row)*DIN + kf);
      ushort4 us;
      us.x = f2bf(v.x*a4.x + c4.x);
      us.y = f2bf(v.y*a4.y + c4.y);
      us.z = f2bf(v.z*a4.z + c4.z);
      us.w = f2bf(v.w*a4.w + c4.w);
      *(ushort4*)(Alds + ((row*256 + kf*2) ^ ((row & 7) << 4))) = us;
    }
  }
  // ---- stage B: bf16 weights, swizzled write
  {
    int kb = (t & 15) * 16;                      // byte offset within 256B row
    #pragma unroll
    for(int it = 0; it < 8; ++it){
      int row = it*16 + (t >> 4);
      uint4 w = *(const uint4*)((const char*)wsrc + row*256 + kb);
      *(uint4*)(Blds + ((row*256 + kb) ^ ((row & 7) << 4))) = w;
    }
  }
  __syncthreads();
  // ---- MFMA: 4 waves, each 64x64 quadrant, 4x4 16x16 tiles x 4 K-steps
  int wv4 = t >> 6, l = t & 63;
  int wr = wv4 >> 1, wc = wv4 & 1;
  int lm = l & 15, lq = l >> 4;
  f32x4 acc[4][4];
  #pragma unroll
  for(int m = 0; m < 4; ++m)
    #pragma unroll
    for(int n = 0; n < 4; ++n) acc[m][n] = (f32x4){0.f,0.f,0.f,0.f};
  #pragma unroll
  for(int kk = 0; kk < 4; ++kk){
    int kbyte = kk*64 + lq*16;
    bf16x8 af[4], bf[4];
    #pragma unroll
    for(int m = 0; m < 4; ++m){
      int row = wr*64 + m*16 + lm;
      af[m] = *(const bf16x8*)(Alds + ((row*256 + kbyte) ^ ((row & 7) << 4)));
    }
    #pragma unroll
    for(int n = 0; n < 4; ++n){
      int row = wc*64 + n*16 + lm;
      bf[n] = *(const bf16x8*)(Blds + ((row*256 + kbyte) ^ ((row & 7) << 4)));
    }
    #pragma unroll
    for(int m = 0; m < 4; ++m)
      #pragma unroll
      for(int n = 0; n < 4; ++n)
        acc[m][n] = __builtin_amdgcn_mfma_f32_16x16x32_bf16(af[m], bf[n], acc[m][n], 0, 0, 0);
  }
  // ---- epilogue: +bias, fp32 store (D layout: col=lane&15, row=(lane>>4)*4+r)
  const float* bias = (mat==0) ? bq : (mat==1) ? bk : bv;
  #pragma unroll
  for(int n = 0; n < 4; ++n){
    float bn = bias[obase + wc*64 + n*16 + lm];
    int gcol = nt*128 + wc*64 + n*16 + lm;
    #pragma unroll
    for(int m = 0; m < 4; ++m){
      int grow0 = mt*128 + wr*64 + m*16 + lq*4;
      #pragma unroll
      for(int r = 0; r < 4; ++r)
        qkv[(size_t)(grow0 + r)*1536 + gcol] = acc[m][n][r] + bn;
    }
  }
}

// ================= K3: k_attn =================
// Per-graph attention, 8 heads fully parallel (wave h = head h), fp32 math.
// S phase: 3x3 register-blocked dots from global QKV (wave dedups 8-lane-shared
// rows); softmax via width-8 shfl_xor; P^T staged in LDS; PV lane=d coalesced
// V reads + broadcast P reads; head-mean via LDS f32 atomics. 3 barriers.
__global__ __launch_bounds__(512)
void k_attn(const float* __restrict__ x, const float* __restrict__ qkv,
            float* __restrict__ ws, float* __restrict__ hcomb){
  __shared__ __align__(16) float ST[8][GSIZE][28];   // P^T per head: [j][r]
  __shared__ __align__(16) float hv[GSIZE][68];      // head-sum accumulator
  int t = threadIdx.x, g = blockIdx.x, base = g * GSIZE;
  int h = t >> 6, l = t & 63;

  for(int i = t; i < GSIZE*68; i += 512) ((float*)hv)[i] = 0.f;

  // ---- S + softmax (per wave: 24x24 scores for head h)
  int r0 = 3*(l >> 3), j0 = 3*(l & 7);
  const float* qp = qkv + (size_t)(base + r0)*1536 + h*64;
  const float* kp = qkv + (size_t)(base + j0)*1536 + 512 + h*64;
  float s00=0.f,s01=0.f,s02=0.f,s10=0.f,s11=0.f,s12=0.f,s20=0.f,s21=0.f,s22=0.f;
  #pragma unroll
  for(int d4 = 0; d4 < 16; ++d4){
    float4 q0 = *(const float4*)(qp + d4*4);
    float4 q1 = *(const float4*)(qp + 1536 + d4*4);
    float4 q2 = *(const float4*)(qp + 3072 + d4*4);
    float4 k0 = *(const float4*)(kp + d4*4);
    float4 k1 = *(const float4*)(kp + 1536 + d4*4);
    float4 k2 = *(const float4*)(kp + 3072 + d4*4);
    s00 += q0.x*k0.x + q0.y*k0.y + q0.z*k0.z + q0.w*k0.w;
    s01 += q0.x*k1.x + q0.y*k1.y + q0.z*k1.z + q0.w*k1.w;
    s02 += q0.x*k2.x + q0.y*k2.y + q0.z*k2.z + q0.w*k2.w;
    s10 += q1.x*k0.x + q1.y*k0.y + q1.z*k0.z + q1.w*k0.w;
    s11 += q1.x*k1.x + q1.y*k1.y + q1.z*k1.z + q1.w*k1.w;
    s12 += q1.x*k2.x + q1.y*k2.y + q1.z*k2.z + q1.w*k2.w;
    s20 += q2.x*k0.x + q2.y*k0.y + q2.z*k0.z + q2.w*k0.w;
    s21 += q2.x*k1.x + q2.y*k1.y + q2.z*k1.z + q2.w*k1.w;
    s22 += q2.x*k2.x + q2.y*k2.y + q2.z*k2.z + q2.w*k2.w;
  }
  {
    float a0, a1, a2, m0, su, inv;
    // row r0+0
    a0 = s00*0.125f; a1 = s01*0.125f; a2 = s02*0.125f;
    m0 = fmaxf(fmaxf(a0, a1), a2);
    #pragma unroll
    for(int o = 1; o < 8; o <<= 1) m0 = fmaxf(m0, __shfl_xor(m0, o, 8));
    a0 = __expf(a0-m0); a1 = __expf(a1-m0); a2 = __expf(a2-m0);
    su = a0 + a1 + a2;
    #pragma unroll
    for(int o = 1; o < 8; o <<= 1) su += __shfl_xor(su, o, 8);
    inv = 1.0f/(su + 1e-16f);
    ST[h][j0+0][r0+0] = a0*inv; ST[h][j0+1][r0+0] = a1*inv; ST[h][j0+2][r0+0] = a2*inv;
    // row r0+1
    a0 = s10*0.125f; a1 = s11*0.125f; a2 = s12*0.125f;
    m0 = fmaxf(fmaxf(a0, a1), a2);
    #pragma unroll
    for(int o = 1; o < 8; o <<= 1) m0 = fmaxf(m0, __shfl_xor(m0, o, 8));
    a0 = __expf(a0-m0); a1 = __expf(a1-m0); a2 = __expf(a2-m0);
    su = a0 + a1 + a2;
    #pragma unroll
    for(int o = 1; o < 8; o <<= 1) su += __shfl_xor(su, o, 8);
    inv = 1.0f/(su + 1e-16f);
    ST[h][j0+0][r0+1] = a0*inv; ST[h][j0+1][r0+1] = a1*inv; ST[h][j0+2][r0+1] = a2*inv;
    // row r0+2
    a0 = s20*0.125f; a1 = s21*0.125f; a2 = s22*0.125f;
    m0 = fmaxf(fmaxf(a0, a1), a2);
    #pragma unroll
    for(int o = 1; o < 8; o <<= 1) m0 = fmaxf(m0, __shfl_xor(m0, o, 8));
    a0 = __expf(a0-m0); a1 = __expf(a1-m0); a2 = __expf(a2-m0);
    su = a0 + a1 + a2;
    #pragma unroll
    for(int o = 1; o < 8; o <<= 1) su += __shfl_xor(su, o, 8);
    inv = 1.0f/(su + 1e-16f);
    ST[h][j0+0][r0+2] = a0*inv; ST[h][j0+1][r0+2] = a1*inv; ST[h][j0+2][r0+2] = a2*inv;
  }
  __syncthreads();   // ST ready (own wave) + hv zeroed for atomics

  // ---- PV: lane l = output dim d; V reads coalesced 256B/row; P broadcast
  {
    float o24[GSIZE];
    #pragma unroll
    for(int r = 0; r < GSIZE; ++r) o24[r] = 0.f;
    const float* vp = qkv + (size_t)base*1536 + 1024 + h*64 + l;
    #pragma unroll
    for(int j = 0; j < GSIZE; ++j){
      float v = vp[(size_t)j*1536];
      #pragma unroll
      for(int rq = 0; rq < 6; ++rq){
        float4 p4 = *(const float4*)&ST[h][j][rq*4];
        o24[rq*4+0] = fmaf(p4.x, v, o24[rq*4+0]);
        o24[rq*4+1] = fmaf(p4.y, v, o24[rq*4+1]);
        o24[rq*4+2] = fmaf(p4.z, v, o24[rq*4+2]);
        o24[rq*4+3] = fmaf(p4.w, v, o24[rq*4+3]);
      }
    }
    #pragma unroll
    for(int r = 0; r < GSIZE; ++r) atomicAdd(&hv[r][l], o24[r]);
  }
  __syncthreads();   // all heads accumulated

  // ---- combine: head mean + residual fold, write hcomb, rebuild hv
  #pragma unroll
  for(int sl = 0; sl < 3; ++sl){
    int idx = t + sl*512;
    int r = idx >> 6, d = idx & 63;
    const float* xr = x + (size_t)(base + r)*DIN;
    float hval = hv[r][d]*0.125f + xr[d] + xr[64 + d];
    hcomb[(size_t)(base + r)*DH + d] = hval;
    hv[r][d] = hval;
  }
  __syncthreads();
  if(t < 64){
    float s1 = 0.f, s2 = 0.f;
    #pragma unroll
    for(int i = 0; i < GSIZE; ++i){ float v = hv[i][t]; s1 += v; s2 += v*v; }
    ws[HP + g*128 + t]      = s1;
    ws[HP + g*128 + 64 + t] = s2;
  }
}

// ================= K4: k_final =================
__global__ __launch_bounds__(256)
void k_final(const float* __restrict__ x,
             const float* __restrict__ hbuf, const float* __restrict__ ws,
             const float* __restrict__ no_w, const float* __restrict__ no_b,
             const float* __restrict__ no_ms,
             const float* __restrict__ pn_w, const float* __restrict__ pn_b,
             const float* __restrict__ pn_ms,
             float* __restrict__ out){
  const float* wt1  = ws + WT1;
  const float* wt2  = ws + WT2;
  const float* pwt1 = ws + PWT1;
  const float* fb   = ws + FBo;

  __shared__ float hs[GSIZE][DH+1];
  __shared__ float hn[GSIZE][DH+1];
  __shared__ float ts[GSIZE][DH+1];
  __shared__ float A2[DH], C2[DH];
  __shared__ float a3[DH], c3[DH];
  __shared__ float scores[GSIZE], wsm[GSIZE];
  __shared__ float redA[256], redB[256];

  int t = threadIdx.x;
  int base = blockIdx.x * GSIZE;

  {
    int c = t & 63, grp = t >> 6;
    float s1 = 0.f, s2 = 0.f;
    for(int p = grp; p < NGRAPH; p += 4){
      s1 += ws[HP + p*128 + c];
      s2 += ws[HP + p*128 + 64 + c];
    }
    redA[t] = s1; redB[t] = s2;
  }
  __syncthreads();
  if(t < DH){
    float s1 = redA[t] + redA[t+64] + redA[t+128] + redA[t+192];
    float s2 = redB[t] + redB[t+64] + redB[t+128] + redB[t+192];
    float mean = s1 * (1.0f / N_NODES);
    float ex2  = s2 * (1.0f / N_NODES);
    float cm   = mean * no_ms[t];
    float var  = ex2 - 2.f*cm*mean + cm*cm;
    float rstd = rsqrtf(var + EPSN);
    float a    = no_w[t] * rstd;
    A2[t] = a; C2[t] = no_b[t] - a*cm;
  }
  __syncthreads();
  for(int p = t; p < GSIZE*DH; p += 256){
    int i = p >> 6, d = p & 63;
    float hvv = hbuf[(size_t)(base+i)*DH + d];
    hs[i][d] = hvv;
    hn[i][d] = A2[d]*hvv + C2[d];
  }
  __syncthreads();
  for(int p = t; p < GSIZE*DH; p += 256){
    int i = p >> 6, c = p & 63;
    float s = fb[c];
    #pragma unroll
    for(int k = 0; k < DH; k++) s += hn[i][k] * wt1[k*DH + c];
    ts[i][c] = gelu_exact(s);
  }
  __syncthreads();
  for(int p = t; p < GSIZE*DH; p += 256){
    int i = p >> 6, c = p & 63;
    float s = fb[64 + c];
    #pragma unroll
    for(int k = 0; k < DH; k++) s += ts[i][k] * wt2[k*DH + c];
    hs[i][c] = hs[i][c] + s;
  }
  __syncthreads();
  if(t < DH){
    float s1 = 0.f, s2 = 0.f;
    for(int i = 0; i < GSIZE; i++){ float v = hs[i][t]; s1 += v; s2 += v*v; }
    float mean = s1 * (1.0f / GSIZE);
    float ex2  = s2 * (1.0f / GSIZE);
    float cm   = mean * pn_ms[t];
    float var  = ex2 - 2.f*cm*mean + cm*cm;
    float rstd = rsqrtf(var + EPSN);
    float a    = pn_w[t] * rstd;
    a3[t] = a; c3[t] = pn_b[t] - a*cm;
  }
  __syncthreads();
  for(int p = t; p < GSIZE*DH; p += 256){
    int i = p >> 6, d = p & 63;
    hn[i][d] = a3[d]*hs[i][d] + c3[d];
  }
  __syncthreads();
  for(int p = t; p < GSIZE*DH; p += 256){
    int i = p >> 6, c = p & 63;
    float s = fb[128 + c];
    #pragma unroll
    for(int k = 0; k < DH; k++) s += hn[i][k] * pwt1[k*DH + c];
    ts[i][c] = gelu_exact(s);
  }
  __syncthreads();
  if(t < GSIZE){
    float s = fb[256];
    for(int c = 0; c < DH; c++) s += ts[t][c] * fb[192 + c];
    scores[t] = s;
  }
  __syncthreads();
  if(t < GSIZE){
    float mx = -1e30f;
    for(int j = 0; j < GSIZE; j++) mx = fmaxf(mx, scores[j]);
    float sum = 0.f;
    for(int j = 0; j < GSIZE; j++) sum += __expf(scores[j] - mx);
    wsm[t] = __expf(scores[t] - mx) / (sum + 1e-16f);
  }
  __syncthreads();
  if(t < DIN){
    float s = 0.f;
    #pragma unroll 8
    for(int i = 0; i < GSIZE; i++) s += wsm[i] * x[(size_t)(base+i)*DIN + t];
    out[(size_t)blockIdx.x*DIN + t] = s;
  }
}

extern "C" void kernel_launch(void* const* d_in, const int* in_sizes, int n_in,
                              void* d_out, int out_size, void* d_ws, size_t ws_size,
                              hipStream_t stream){
  (void)in_sizes; (void)n_in; (void)out_size; (void)ws_size;
  const float* x    = (const float*)d_in[0];
  const float* nq_w = (const float*)d_in[4];
  const float* nq_b = (const float*)d_in[5];
  const float* nq_ms= (const float*)d_in[6];
  const float* wq   = (const float*)d_in[7];
  const float* bq   = (const float*)d_in[8];
  const float* wk   = (const float*)d_in[9];
  const float* bk   = (const float*)d_in[10];
  const float* wv   = (const float*)d_in[11];
  const float* bv   = (const float*)d_in[12];
  const float* no_w = (const float*)d_in[13];
  const float* no_b = (const float*)d_in[14];
  const float* no_ms= (const float*)d_in[15];
  const float* o_w1 = (const float*)d_in[16];
  const float* o_b1 = (const float*)d_in[17];
  const float* o_w2 = (const float*)d_in[18];
  const float* o_b2 = (const float*)d_in[19];
  const float* pn_w = (const float*)d_in[20];
  const float* pn_b = (const float*)d_in[21];
  const float* pn_ms= (const float*)d_in[22];
  const float* p_w1 = (const float*)d_in[23];
  const float* p_b1 = (const float*)d_in[24];
  const float* p_w2 = (const float*)d_in[25];
  const float* p_b2 = (const float*)d_in[26];

  float* ws    = (float*)d_ws;
  float* hcomb = (float*)((char*)d_ws + HCOMB_BYTE);
  float* qkvb  = (float*)((char*)d_ws + QKV_BYTE);

  k_pre<<<207, 256, 0, stream>>>(x, o_w1, o_w2, p_w1, o_b1, o_b2, p_b1, p_w2, p_b2,
                                 wq, wk, wv, ws);
  k_stats<<<1, 512, 0, stream>>>(nq_w, nq_b, nq_ms, ws);
  k_qkv<<<576, 256, 0, stream>>>(x, bq, bk, bv, ws, qkvb);
  k_attn<<<NGRAPH, 512, 0, stream>>>(x, qkvb, ws, hcomb);
  k_final<<<NGRAPH, 256, 0, stream>>>(x, hcomb, ws, no_w, no_b, no_ms,
                                      pn_w, pn_b, pn_ms, (float*)d_out);
}

// Round 2
// 195.595 us; speedup vs baseline: 1.0347x; 1.0347x over previous
//
#include <hip/hip_runtime.h>
#include <stdint.h>

// FP32 in/out. bf16 only for MFMA operands.
// R15: k_final was the hidden co-bottleneck (49.7us, 1 block/CU, occupancy
// 9.5%, VALUBusy 7.5%): per-block redundant HP reduce (256x) + inner-loop
// scalar weight loads gone HBM-cold after 38MB QKV traffic flushed L2.
// Fix: k_hstats computes A2/C2 once; k_final stages W1/W2/PW1/fb into LDS
// in one coalesced burst, 6-row register-blocked MLP (weight reuse x6),
// pn-norm fused into PW1 operand. Barriers 10->7.
// Ledger: R14 split k_fused -> k_stats+k_qkv+k_attn (k_fused 40.2 -> sum
// smaller, but k_final regressed +12us via L2 flush). R6 mega-kernel +150us;
// R8 union prefetch spills; R10 launch_bounds spill; R12 fused softmax spill.

#define N_NODES 6144
#define GSIZE 24
#define NGRAPH 256
#define DIN 128
#define DH 64
#define EFF 512
#define EPSN 1e-5f

typedef __attribute__((ext_vector_type(8))) __bf16 bf16x8;
typedef __attribute__((ext_vector_type(4))) float f32x4;
union U16B { uint4 u; bf16x8 v; unsigned short s[8]; };

__device__ inline float bf2f(unsigned short u){ return __uint_as_float(((unsigned)u)<<16); }
__device__ inline unsigned short f2bf(float f){
  unsigned u = __float_as_uint(f);
  u += 0x7fff + ((u>>16)&1);
  return (unsigned short)(u>>16);
}
__device__ inline float gelu_exact(float x){ return 0.5f*x*(1.0f+erff(x*0.70710678118654752f)); }

// ---- workspace float offsets ----
#define XP    0         // 192 x 256 floats: x col sum/sumsq partials
#define HP    49152     // 256 x 128 floats: h col stat partials
#define WT1   81920
#define WT2   86016
#define PWT1  90112
#define FBo   94208     // 257 floats
#define AC    94720     // 128+128 floats: x-norm A1/C1
#define AC2   94976     // 64+64 floats: h-norm A2/C2
#define WCVT_BYTE  385024   // 3 x 512 x 128 bf16 = 393216 B
#define HCOMB_BYTE 778240   // 6144 x 64 fp32 -> ends 2351104
#define QKV_BYTE   2359296  // 6144 x 1536 fp32 = 37.75 MB

// ================= K1: k_pre =================
__global__ __launch_bounds__(256)
void k_pre(const float* __restrict__ x,
           const float* __restrict__ o_w1, const float* __restrict__ o_w2,
           const float* __restrict__ p_w1,
           const float* __restrict__ o_b1, const float* __restrict__ o_b2,
           const float* __restrict__ p_b1, const float* __restrict__ p_w2,
           const float* __restrict__ p_b2,
           const float* __restrict__ wq, const float* __restrict__ wk,
           const float* __restrict__ wv,
           float* __restrict__ wsf){
  int t = threadIdx.x;
  int bi = blockIdx.x;
  if(bi < 192){
    int c = t & 127, h = t >> 7;
    float s = 0.f, q = 0.f;
    #pragma unroll
    for(int r = 0; r < 16; ++r){
      float v = x[(size_t)(bi*32 + h + 2*r)*DIN + c];
      s += v; q += v*v;
    }
    __shared__ float sm[256], sm2[256];
    sm[t] = s; sm2[t] = q;
    __syncthreads();
    if(t < 128){
      wsf[XP + bi*256 + t]       = sm[t] + sm[t+128];
      wsf[XP + bi*256 + 128 + t] = sm2[t] + sm2[t+128];
    }
    return;
  }
  if(bi < 195){
    const float* src; float* dst;
    if(bi == 192){ src = o_w1; dst = wsf + WT1; }
    else if(bi == 193){ src = o_w2; dst = wsf + WT2; }
    else { src = p_w1; dst = wsf + PWT1; }
    for(int p = t; p < DH*DH; p += 256){
      int r = p >> 6, c = p & 63;
      dst[c*DH + r] = src[p];
    }
    if(bi == 192){
      float* fb = wsf + FBo;
      if(t < 64){
        fb[t]       = o_b1[t];
        fb[64 + t]  = o_b2[t];
        fb[128 + t] = p_b1[t];
        fb[192 + t] = p_w2[t];
      }
      if(t == 0) fb[256] = p_b2[0];
    }
    return;
  }
  int j = bi - 195;               // 0..11
  int mat = j >> 2, seg = j & 3;
  const float* src = (mat==0) ? wq : (mat==1) ? wk : wv;
  unsigned short* dst = (unsigned short*)((char*)wsf + WCVT_BYTE)
                        + (size_t)mat*EFF*DIN + seg*16384;
  const float* sp = src + seg*16384;
  for(int e = t*8; e < 16384; e += 2048){
    float4 a = *(const float4*)(sp + e);
    float4 b = *(const float4*)(sp + e + 4);
    U16B o;
    o.s[0]=f2bf(a.x); o.s[1]=f2bf(a.y); o.s[2]=f2bf(a.z); o.s[3]=f2bf(a.w);
    o.s[4]=f2bf(b.x); o.s[5]=f2bf(b.y); o.s[6]=f2bf(b.z); o.s[7]=f2bf(b.w);
    *(uint4*)(dst + e) = o.u;
  }
}

// ================= K1.5: k_stats =================
__global__ __launch_bounds__(512)
void k_stats(const float* __restrict__ nq_w, const float* __restrict__ nq_b,
             const float* __restrict__ nq_ms, float* __restrict__ ws){
  __shared__ float redA[512], redB[512];
  int t = threadIdx.x;
  int c = t & 127, grp = t >> 7;
  float s = 0.f, q = 0.f;
  for(int p = grp*48; p < grp*48 + 48; ++p){
    s += ws[XP + p*256 + c];
    q += ws[XP + p*256 + 128 + c];
  }
  redA[t] = s; redB[t] = q;
  __syncthreads();
  if(t < 128){
    float s1 = redA[t] + redA[t+128] + redA[t+256] + redA[t+384];
    float q1 = redB[t] + redB[t+128] + redB[t+256] + redB[t+384];
    float mean = s1 * (1.0f / N_NODES);
    float ex2  = q1 * (1.0f / N_NODES);
    float cm   = mean * nq_ms[t];
    float var  = ex2 - 2.f*cm*mean + cm*cm;
    float rstd = rsqrtf(var + EPSN);
    float a    = nq_w[t] * rstd;
    ws[AC + t]       = a;
    ws[AC + 128 + t] = nq_b[t] - a*cm;
  }
}

// ================= K2: k_qkv =================
__global__ __launch_bounds__(256)
void k_qkv(const float* __restrict__ x,
           const float* __restrict__ bq, const float* __restrict__ bk,
           const float* __restrict__ bv,
           const float* __restrict__ ws, float* __restrict__ qkv){
  __shared__ __align__(16) char lds[65536];
  char* Alds = lds;            // x-hat bf16 [128][128]
  char* Blds = lds + 32768;    // W bf16 [128][128]
  int t = threadIdx.x;
  int mt = blockIdx.x / 12, nt = blockIdx.x % 12;
  int mat = nt >> 2, obase = (nt & 3) * 128;
  const float* A1c = ws + AC;
  const unsigned short* wsrc = (const unsigned short*)((const char*)ws + WCVT_BYTE)
                               + (size_t)mat*EFF*DIN + (size_t)obase*DIN;
  {
    int kf = (t & 31) * 4;
    float4 a4 = *(const float4*)(A1c + kf);
    float4 c4 = *(const float4*)(A1c + 128 + kf);
    #pragma unroll
    for(int it = 0; it < 16; ++it){
      int row = it*8 + (t >> 5);
      float4 v = *(const float4*)(x + (size_t)(mt*128 + row)*DIN + kf);
      ushort4 us;
      us.x = f2bf(v.x*a4.x + c4.x);
      us.y = f2bf(v.y*a4.y + c4.y);
      us.z = f2bf(v.z*a4.z + c4.z);
      us.w = f2bf(v.w*a4.w + c4.w);
      *(ushort4*)(Alds + ((row*256 + kf*2) ^ ((row & 7) << 4))) = us;
    }
  }
  {
    int kb = (t & 15) * 16;
    #pragma unroll
    for(int it = 0; it < 8; ++it){
      int row = it*16 + (t >> 4);
      uint4 w = *(const uint4*)((const char*)wsrc + row*256 + kb);
      *(uint4*)(Blds + ((row*256 + kb) ^ ((row & 7) << 4))) = w;
    }
  }
  __syncthreads();
  int wv4 = t >> 6, l = t & 63;
  int wr = wv4 >> 1, wc = wv4 & 1;
  int lm = l & 15, lq = l >> 4;
  f32x4 acc[4][4];
  #pragma unroll
  for(int m = 0; m < 4; ++m)
    #pragma unroll
    for(int n = 0; n < 4; ++n) acc[m][n] = (f32x4){0.f,0.f,0.f,0.f};
  #pragma unroll
  for(int kk = 0; kk < 4; ++kk){
    int kbyte = kk*64 + lq*16;
    bf16x8 af[4], bf[4];
    #pragma unroll
    for(int m = 0; m < 4; ++m){
      int row = wr*64 + m*16 + lm;
      af[m] = *(const bf16x8*)(Alds + ((row*256 + kbyte) ^ ((row & 7) << 4)));
    }
    #pragma unroll
    for(int n = 0; n < 4; ++n){
      int row = wc*64 + n*16 + lm;
      bf[n] = *(const bf16x8*)(Blds + ((row*256 + kbyte) ^ ((row & 7) << 4)));
    }
    #pragma unroll
    for(int m = 0; m < 4; ++m)
      #pragma unroll
      for(int n = 0; n < 4; ++n)
        acc[m][n] = __builtin_amdgcn_mfma_f32_16x16x32_bf16(af[m], bf[n], acc[m][n], 0, 0, 0);
  }
  const float* bias = (mat==0) ? bq : (mat==1) ? bk : bv;
  #pragma unroll
  for(int n = 0; n < 4; ++n){
    float bn = bias[obase + wc*64 + n*16 + lm];
    int gcol = nt*128 + wc*64 + n*16 + lm;
    #pragma unroll
    for(int m = 0; m < 4; ++m){
      int grow0 = mt*128 + wr*64 + m*16 + lq*4;
      #pragma unroll
      for(int r = 0; r < 4; ++r)
        qkv[(size_t)(grow0 + r)*1536 + gcol] = acc[m][n][r] + bn;
    }
  }
}

// ================= K3: k_attn =================
__global__ __launch_bounds__(512)
void k_attn(const float* __restrict__ x, const float* __restrict__ qkv,
            float* __restrict__ ws, float* __restrict__ hcomb){
  __shared__ __align__(16) float ST[8][GSIZE][28];   // P^T per head: [j][r]
  __shared__ __align__(16) float hv[GSIZE][68];      // head-sum accumulator
  int t = threadIdx.x, g = blockIdx.x, base = g * GSIZE;
  int h = t >> 6, l = t & 63;

  for(int i = t; i < GSIZE*68; i += 512) ((float*)hv)[i] = 0.f;

  int r0 = 3*(l >> 3), j0 = 3*(l & 7);
  const float* qp = qkv + (size_t)(base + r0)*1536 + h*64;
  const float* kp = qkv + (size_t)(base + j0)*1536 + 512 + h*64;
  float s00=0.f,s01=0.f,s02=0.f,s10=0.f,s11=0.f,s12=0.f,s20=0.f,s21=0.f,s22=0.f;
  #pragma unroll
  for(int d4 = 0; d4 < 16; ++d4){
    float4 q0 = *(const float4*)(qp + d4*4);
    float4 q1 = *(const float4*)(qp + 1536 + d4*4);
    float4 q2 = *(const float4*)(qp + 3072 + d4*4);
    float4 k0 = *(const float4*)(kp + d4*4);
    float4 k1 = *(const float4*)(kp + 1536 + d4*4);
    float4 k2 = *(const float4*)(kp + 3072 + d4*4);
    s00 += q0.x*k0.x + q0.y*k0.y + q0.z*k0.z + q0.w*k0.w;
    s01 += q0.x*k1.x + q0.y*k1.y + q0.z*k1.z + q0.w*k1.w;
    s02 += q0.x*k2.x + q0.y*k2.y + q0.z*k2.z + q0.w*k2.w;
    s10 += q1.x*k0.x + q1.y*k0.y + q1.z*k0.z + q1.w*k0.w;
    s11 += q1.x*k1.x + q1.y*k1.y + q1.z*k1.z + q1.w*k1.w;
    s12 += q1.x*k2.x + q1.y*k2.y + q1.z*k2.z + q1.w*k2.w;
    s20 += q2.x*k0.x + q2.y*k0.y + q2.z*k0.z + q2.w*k0.w;
    s21 += q2.x*k1.x + q2.y*k1.y + q2.z*k1.z + q2.w*k1.w;
    s22 += q2.x*k2.x + q2.y*k2.y + q2.z*k2.z + q2.w*k2.w;
  }
  {
    float a0, a1, a2, m0, su, inv;
    a0 = s00*0.125f; a1 = s01*0.125f; a2 = s02*0.125f;
    m0 = fmaxf(fmaxf(a0, a1), a2);
    #pragma unroll
    for(int o = 1; o < 8; o <<= 1) m0 = fmaxf(m0, __shfl_xor(m0, o, 8));
    a0 = __expf(a0-m0); a1 = __expf(a1-m0); a2 = __expf(a2-m0);
    su = a0 + a1 + a2;
    #pragma unroll
    for(int o = 1; o < 8; o <<= 1) su += __shfl_xor(su, o, 8);
    inv = 1.0f/(su + 1e-16f);
    ST[h][j0+0][r0+0] = a0*inv; ST[h][j0+1][r0+0] = a1*inv; ST[h][j0+2][r0+0] = a2*inv;
    a0 = s10*0.125f; a1 = s11*0.125f; a2 = s12*0.125f;
    m0 = fmaxf(fmaxf(a0, a1), a2);
    #pragma unroll
    for(int o = 1; o < 8; o <<= 1) m0 = fmaxf(m0, __shfl_xor(m0, o, 8));
    a0 = __expf(a0-m0); a1 = __expf(a1-m0); a2 = __expf(a2-m0);
    su = a0 + a1 + a2;
    #pragma unroll
    for(int o = 1; o < 8; o <<= 1) su += __shfl_xor(su, o, 8);
    inv = 1.0f/(su + 1e-16f);
    ST[h][j0+0][r0+1] = a0*inv; ST[h][j0+1][r0+1] = a1*inv; ST[h][j0+2][r0+1] = a2*inv;
    a0 = s20*0.125f; a1 = s21*0.125f; a2 = s22*0.125f;
    m0 = fmaxf(fmaxf(a0, a1), a2);
    #pragma unroll
    for(int o = 1; o < 8; o <<= 1) m0 = fmaxf(m0, __shfl_xor(m0, o, 8));
    a0 = __expf(a0-m0); a1 = __expf(a1-m0); a2 = __expf(a2-m0);
    su = a0 + a1 + a2;
    #pragma unroll
    for(int o = 1; o < 8; o <<= 1) su += __shfl_xor(su, o, 8);
    inv = 1.0f/(su + 1e-16f);
    ST[h][j0+0][r0+2] = a0*inv; ST[h][j0+1][r0+2] = a1*inv; ST[h][j0+2][r0+2] = a2*inv;
  }
  __syncthreads();

  {
    float o24[GSIZE];
    #pragma unroll
    for(int r = 0; r < GSIZE; ++r) o24[r] = 0.f;
    const float* vp = qkv + (size_t)base*1536 + 1024 + h*64 + l;
    #pragma unroll
    for(int j = 0; j < GSIZE; ++j){
      float v = vp[(size_t)j*1536];
      #pragma unroll
      for(int rq = 0; rq < 6; ++rq){
        float4 p4 = *(const float4*)&ST[h][j][rq*4];
        o24[rq*4+0] = fmaf(p4.x, v, o24[rq*4+0]);
        o24[rq*4+1] = fmaf(p4.y, v, o24[rq*4+1]);
        o24[rq*4+2] = fmaf(p4.z, v, o24[rq*4+2]);
        o24[rq*4+3] = fmaf(p4.w, v, o24[rq*4+3]);
      }
    }
    #pragma unroll
    for(int r = 0; r < GSIZE; ++r) atomicAdd(&hv[r][l], o24[r]);
  }
  __syncthreads();

  #pragma unroll
  for(int sl = 0; sl < 3; ++sl){
    int idx = t + sl*512;
    int r = idx >> 6, d = idx & 63;
    const float* xr = x + (size_t)(base + r)*DIN;
    float hval = hv[r][d]*0.125f + xr[d] + xr[64 + d];
    hcomb[(size_t)(base + r)*DH + d] = hval;
    hv[r][d] = hval;
  }
  __syncthreads();
  if(t < 64){
    float s1 = 0.f, s2 = 0.f;
    #pragma unroll
    for(int i = 0; i < GSIZE; ++i){ float v = hv[i][t]; s1 += v; s2 += v*v; }
    ws[HP + g*128 + t]      = s1;
    ws[HP + g*128 + 64 + t] = s2;
  }
}

// ================= K3.5: k_hstats =================
// Reduce HP partials -> A2/C2 once (was redundantly done by all 256 k_final blocks).
__global__ __launch_bounds__(256)
void k_hstats(const float* __restrict__ no_w, const float* __restrict__ no_b,
              const float* __restrict__ no_ms, float* __restrict__ ws){
  __shared__ float redA[256], redB[256];
  int t = threadIdx.x;
  int c = t & 63, grp = t >> 6;
  float s1 = 0.f, s2 = 0.f;
  for(int p = grp; p < NGRAPH; p += 4){
    s1 += ws[HP + p*128 + c];
    s2 += ws[HP + p*128 + 64 + c];
  }
  redA[t] = s1; redB[t] = s2;
  __syncthreads();
  if(t < DH){
    float a1 = redA[t] + redA[t+64] + redA[t+128] + redA[t+192];
    float a2 = redB[t] + redB[t+64] + redB[t+128] + redB[t+192];
    float mean = a1 * (1.0f / N_NODES);
    float ex2  = a2 * (1.0f / N_NODES);
    float cm   = mean * no_ms[t];
    float var  = ex2 - 2.f*cm*mean + cm*cm;
    float rstd = rsqrtf(var + EPSN);
    float a    = no_w[t] * rstd;
    ws[AC2 + t]      = a;
    ws[AC2 + 64 + t] = no_b[t] - a*cm;
  }
}

// ================= K4: k_final =================
// Per-graph tail. Weights bulk-staged into LDS (one coalesced burst), 6-row
// register-blocked MLPs (each staged weight reused 6x via LDS broadcast of hn),
// pn-norm fused into PW1 operand. 7 barriers, no global reduce.
__global__ __launch_bounds__(256)
void k_final(const float* __restrict__ x,
             const float* __restrict__ hbuf, const float* __restrict__ ws,
             const float* __restrict__ pn_w, const float* __restrict__ pn_b,
             const float* __restrict__ pn_ms,
             float* __restrict__ out){
  __shared__ __align__(16) float W1[4096];
  __shared__ __align__(16) float W2[4096];
  __shared__ __align__(16) float PW1[4096];
  __shared__ __align__(16) float fbs[260];
  __shared__ __align__(16) float hs[GSIZE][68];
  __shared__ __align__(16) float hn[GSIZE][68];
  __shared__ __align__(16) float ts[GSIZE][68];
  __shared__ float a3[DH], c3[DH];
  __shared__ float scores[GSIZE], wsm[GSIZE];

  int t = threadIdx.x;
  int base = blockIdx.x * GSIZE;
  int c = t & 63, i0 = t >> 6;      // col + first row; rows i0+4r, r=0..5

  // ---- stage weights + fb (coalesced float4 burst; 12 loads/thread) ----
  {
    const float4* s1 = (const float4*)(ws + WT1);
    const float4* s2 = (const float4*)(ws + WT2);
    const float4* s3 = (const float4*)(ws + PWT1);
    #pragma unroll
    for(int it = 0; it < 4; ++it){
      int i = t + it*256;
      ((float4*)W1)[i]  = s1[i];
      ((float4*)W2)[i]  = s2[i];
      ((float4*)PW1)[i] = s3[i];
    }
    if(t < 257) fbs[t] = ws[FBo + t];
  }
  // ---- load h rows + apply global h-norm (A2/C2 precomputed) ----
  {
    float a2 = ws[AC2 + c];
    float c2 = ws[AC2 + 64 + c];
    #pragma unroll
    for(int r = 0; r < 6; ++r){
      int i = i0 + 4*r;
      float hvv = hbuf[(size_t)(base + i)*DH + c];
      hs[i][c] = hvv;
      hn[i][c] = a2*hvv + c2;
    }
  }
  __syncthreads();

  // ---- FF1: ts = gelu(hn @ W1 + b1), 6 rows/thread ----
  {
    float acc[6];
    #pragma unroll
    for(int r = 0; r < 6; ++r) acc[r] = fbs[c];
    #pragma unroll 16
    for(int k = 0; k < DH; ++k){
      float w = W1[k*DH + c];
      #pragma unroll
      for(int r = 0; r < 6; ++r) acc[r] = fmaf(hn[i0 + 4*r][k], w, acc[r]);
    }
    #pragma unroll
    for(int r = 0; r < 6; ++r) ts[i0 + 4*r][c] = gelu_exact(acc[r]);
  }
  __syncthreads();

  // ---- FF2: hs += ts @ W2 + b2  (h2) ----
  {
    float acc[6];
    #pragma unroll
    for(int r = 0; r < 6; ++r) acc[r] = fbs[64 + c];
    #pragma unroll 16
    for(int k = 0; k < DH; ++k){
      float w = W2[k*DH + c];
      #pragma unroll
      for(int r = 0; r < 6; ++r) acc[r] = fmaf(ts[i0 + 4*r][k], w, acc[r]);
    }
    #pragma unroll
    for(int r = 0; r < 6; ++r) hs[i0 + 4*r][c] += acc[r];
  }
  __syncthreads();

  // ---- per-graph pn-norm stats ----
  if(t < DH){
    float s1 = 0.f, s2 = 0.f;
    #pragma unroll
    for(int i = 0; i < GSIZE; i++){ float v = hs[i][t]; s1 += v; s2 += v*v; }
    float mean = s1 * (1.0f / GSIZE);
    float ex2  = s2 * (1.0f / GSIZE);
    float cm   = mean * pn_ms[t];
    float var  = ex2 - 2.f*cm*mean + cm*cm;
    float rstd = rsqrtf(var + EPSN);
    float a    = pn_w[t] * rstd;
    a3[t] = a; c3[t] = pn_b[t] - a*cm;
  }
  __syncthreads();

  // ---- PW1 MLP with pn-norm fused into operand: ts = gelu((a3*hs+c3) @ PW1 + pb1) ----
  {
    float acc[6];
    #pragma unroll
    for(int r = 0; r < 6; ++r) acc[r] = fbs[128 + c];
    #pragma unroll 16
    for(int k = 0; k < DH; ++k){
      float w  = PW1[k*DH + c];
      float ak = a3[k], ck = c3[k];
      #pragma unroll
      for(int r = 0; r < 6; ++r){
        float hnv = fmaf(ak, hs[i0 + 4*r][k], ck);
        acc[r] = fmaf(hnv, w, acc[r]);
      }
    }
    #pragma unroll
    for(int r = 0; r < 6; ++r) ts[i0 + 4*r][c] = gelu_exact(acc[r]);
  }
  __syncthreads();

  // ---- scores = ts @ p_w2 + pb2 ----
  if(t < GSIZE){
    const float4* tp = (const float4*)ts[t];
    const float4* wp = (const float4*)(fbs + 192);
    float s = fbs[256];
    #pragma unroll
    for(int q = 0; q < 16; ++q){
      float4 a = tp[q], b = wp[q];
      s += a.x*b.x + a.y*b.y + a.z*b.z + a.w*b.w;
    }
    scores[t] = s;
  }
  __syncthreads();
  if(t < GSIZE){
    float mx = -1e30f;
    #pragma unroll
    for(int j = 0; j < GSIZE; j++) mx = fmaxf(mx, scores[j]);
    float sum = 0.f;
    #pragma unroll
    for(int j = 0; j < GSIZE; j++) sum += __expf(scores[j] - mx);
    wsm[t] = __expf(scores[t] - mx) / (sum + 1e-16f);
  }
  __syncthreads();
  if(t < DIN){
    float s = 0.f;
    #pragma unroll 8
    for(int i = 0; i < GSIZE; i++) s += wsm[i] * x[(size_t)(base+i)*DIN + t];
    out[(size_t)blockIdx.x*DIN + t] = s;
  }
}

extern "C" void kernel_launch(void* const* d_in, const int* in_sizes, int n_in,
                              void* d_out, int out_size, void* d_ws, size_t ws_size,
                              hipStream_t stream){
  (void)in_sizes; (void)n_in; (void)out_size; (void)ws_size;
  const float* x    = (const float*)d_in[0];
  const float* nq_w = (const float*)d_in[4];
  const float* nq_b = (const float*)d_in[5];
  const float* nq_ms= (const float*)d_in[6];
  const float* wq   = (const float*)d_in[7];
  const float* bq   = (const float*)d_in[8];
  const float* wk   = (const float*)d_in[9];
  const float* bk   = (const float*)d_in[10];
  const float* wv   = (const float*)d_in[11];
  const float* bv   = (const float*)d_in[12];
  const float* no_w = (const float*)d_in[13];
  const float* no_b = (const float*)d_in[14];
  const float* no_ms= (const float*)d_in[15];
  const float* o_w1 = (const float*)d_in[16];
  const float* o_b1 = (const float*)d_in[17];
  const float* o_w2 = (const float*)d_in[18];
  const float* o_b2 = (const float*)d_in[19];
  const float* pn_w = (const float*)d_in[20];
  const float* pn_b = (const float*)d_in[21];
  const float* pn_ms= (const float*)d_in[22];
  const float* p_w1 = (const float*)d_in[23];
  const float* p_b1 = (const float*)d_in[24];
  const float* p_w2 = (const float*)d_in[25];
  const float* p_b2 = (const float*)d_in[26];

  float* ws    = (float*)d_ws;
  float* hcomb = (float*)((char*)d_ws + HCOMB_BYTE);
  float* qkvb  = (float*)((char*)d_ws + QKV_BYTE);

  k_pre<<<207, 256, 0, stream>>>(x, o_w1, o_w2, p_w1, o_b1, o_b2, p_b1, p_w2, p_b2,
                                 wq, wk, wv, ws);
  k_stats<<<1, 512, 0, stream>>>(nq_w, nq_b, nq_ms, ws);
  k_qkv<<<576, 256, 0, stream>>>(x, bq, bk, bv, ws, qkvb);
  k_attn<<<NGRAPH, 512, 0, stream>>>(x, qkvb, ws, hcomb);
  k_hstats<<<1, 256, 0, stream>>>(no_w, no_b, no_ms, ws);
  k_final<<<NGRAPH, 256, 0, stream>>>(x, hcomb, ws, pn_w, pn_b, pn_ms, (float*)d_out);
}

// Round 3
// 181.029 us; speedup vs baseline: 1.1180x; 1.0805x over previous
//
#include <hip/hip_runtime.h>
#include <stdint.h>

// FP32 in/out. bf16 only for MFMA operands.
// R16 consolidation: 6 launches -> 3. k_qkv+k_attn fused into k_attn2:
// block = 1 graph, wave h computes head h's Q/K/V cols into LDS (fp32,
// [3][24][516]) via MFMA, then S/softmax/PV read only wave-own columns ->
// ZERO barriers between GEMM and attention (4 barriers total vs 15 in R8).
// Kills the 75MB QKV HBM round-trip. k_stats/k_hstats folded as redundant
// per-block reduces of L3-hot partials (XP 192KB / HP 128KB).
// Ledger: R15 k_final LDS-staged MLP (49.7 -> <45, proved 72KB static LDS
// compiles); R14 split (k_fused 40 -> pieces, +L2-flush regression on
// k_final); R6 mega-kernel +150us (per-block full-weight reload -- NOT the
// same as this: here weights are read once per block, 384KB L2-shared).

#define N_NODES 6144
#define GSIZE 24
#define NGRAPH 256
#define DIN 128
#define DH 64
#define EFF 512
#define EPSN 1e-5f

typedef __attribute__((ext_vector_type(8))) __bf16 bf16x8;
typedef __attribute__((ext_vector_type(4))) float f32x4;
union U16B { uint4 u; bf16x8 v; unsigned short s[8]; };

__device__ inline unsigned short f2bf(float f){
  unsigned u = __float_as_uint(f);
  u += 0x7fff + ((u>>16)&1);
  return (unsigned short)(u>>16);
}
__device__ inline float gelu_exact(float x){ return 0.5f*x*(1.0f+erff(x*0.70710678118654752f)); }

// ---- workspace float offsets ----
#define XP    0         // 192 x 256 floats: x col sum/sumsq partials
#define HP    49152     // 256 x 128 floats: h col stat partials
#define WT1   81920
#define WT2   86016
#define PWT1  90112
#define FBo   94208     // 257 floats
#define WCVT_BYTE  385024   // 3 x 512 x 128 bf16 = 393216 B
#define HCOMB_BYTE 778240   // 6144 x 64 fp32

#define QSTRIDE 516     // fp32 row stride for LDS QKV (padded)

// ================= K1: k_pre =================
__global__ __launch_bounds__(256)
void k_pre(const float* __restrict__ x,
           const float* __restrict__ o_w1, const float* __restrict__ o_w2,
           const float* __restrict__ p_w1,
           const float* __restrict__ o_b1, const float* __restrict__ o_b2,
           const float* __restrict__ p_b1, const float* __restrict__ p_w2,
           const float* __restrict__ p_b2,
           const float* __restrict__ wq, const float* __restrict__ wk,
           const float* __restrict__ wv,
           float* __restrict__ wsf){
  int t = threadIdx.x;
  int bi = blockIdx.x;
  if(bi < 192){
    int c = t & 127, h = t >> 7;
    float s = 0.f, q = 0.f;
    #pragma unroll
    for(int r = 0; r < 16; ++r){
      float v = x[(size_t)(bi*32 + h + 2*r)*DIN + c];
      s += v; q += v*v;
    }
    __shared__ float sm[256], sm2[256];
    sm[t] = s; sm2[t] = q;
    __syncthreads();
    if(t < 128){
      wsf[XP + bi*256 + t]       = sm[t] + sm[t+128];
      wsf[XP + bi*256 + 128 + t] = sm2[t] + sm2[t+128];
    }
    return;
  }
  if(bi < 195){
    const float* src; float* dst;
    if(bi == 192){ src = o_w1; dst = wsf + WT1; }
    else if(bi == 193){ src = o_w2; dst = wsf + WT2; }
    else { src = p_w1; dst = wsf + PWT1; }
    for(int p = t; p < DH*DH; p += 256){
      int r = p >> 6, c = p & 63;
      dst[c*DH + r] = src[p];
    }
    if(bi == 192){
      float* fb = wsf + FBo;
      if(t < 64){
        fb[t]       = o_b1[t];
        fb[64 + t]  = o_b2[t];
        fb[128 + t] = p_b1[t];
        fb[192 + t] = p_w2[t];
      }
      if(t == 0) fb[256] = p_b2[0];
    }
    return;
  }
  int j = bi - 195;               // 0..11
  int mat = j >> 2, seg = j & 3;
  const float* src = (mat==0) ? wq : (mat==1) ? wk : wv;
  unsigned short* dst = (unsigned short*)((char*)wsf + WCVT_BYTE)
                        + (size_t)mat*EFF*DIN + seg*16384;
  const float* sp = src + seg*16384;
  for(int e = t*8; e < 16384; e += 2048){
    float4 a = *(const float4*)(sp + e);
    float4 b = *(const float4*)(sp + e + 4);
    U16B o;
    o.s[0]=f2bf(a.x); o.s[1]=f2bf(a.y); o.s[2]=f2bf(a.z); o.s[3]=f2bf(a.w);
    o.s[4]=f2bf(b.x); o.s[5]=f2bf(b.y); o.s[6]=f2bf(b.z); o.s[7]=f2bf(b.w);
    *(uint4*)(dst + e) = o.u;
  }
}

// ================= K2: k_attn2 =================
// Block = 1 graph (24 nodes), 512 thr = 8 waves = 8 heads.
// LDS: QKV fp32 [3][24][516] (148.6KB) + hv (6.5KB) + A1s/C1s (1KB) = 156KB.
// Phases: [stats reduce] 2 bar | [QKV MFMA -> LDS, wave-own cols, no bar]
// [S+softmax -> ST overlay on Q_h, wave-local] [PV -> hv atomics] bar |
// [combine+hcomb+HP] bar.
__global__ __launch_bounds__(512)
void k_attn2(const float* __restrict__ x,
             const float* __restrict__ bq, const float* __restrict__ bk,
             const float* __restrict__ bv,
             const float* __restrict__ nq_w, const float* __restrict__ nq_b,
             const float* __restrict__ nq_ms,
             float* __restrict__ ws, float* __restrict__ hcomb){
  __shared__ __align__(16) float qlds[3*GSIZE*QSTRIDE];  // 148,608 B
  __shared__ __align__(16) float hv[GSIZE][68];          // 6,528 B
  __shared__ float A1s[DIN], C1s[DIN];                   // 1,024 B

  int t = threadIdx.x, g = blockIdx.x, base = g*GSIZE;
  int h = t >> 6, l = t & 63;
  const unsigned short* wcvt = (const unsigned short*)((const char*)ws + WCVT_BYTE);

  for(int i = t; i < GSIZE*68; i += 512) ((float*)hv)[i] = 0.f;

  // ---- redundant x-stat reduce (XP is L3-hot; same summation order as old k_stats)
  {
    float* redA = qlds;           // alias QKV space (dead until after barrier 2)
    float* redB = qlds + 512;
    int c = t & 127, grp = t >> 7;
    float s = 0.f, q = 0.f;
    for(int p = grp*48; p < grp*48 + 48; ++p){
      s += ws[XP + p*256 + c];
      q += ws[XP + p*256 + 128 + c];
    }
    redA[t] = s; redB[t] = q;
    __syncthreads();
    if(t < 128){
      float s1 = redA[t] + redA[t+128] + redA[t+256] + redA[t+384];
      float q1 = redB[t] + redB[t+128] + redB[t+256] + redB[t+384];
      float mean = s1 * (1.0f / N_NODES);
      float ex2  = q1 * (1.0f / N_NODES);
      float cm   = mean * nq_ms[t];
      float var  = ex2 - 2.f*cm*mean + cm*cm;
      float rstd = rsqrtf(var + EPSN);
      float a    = nq_w[t] * rstd;
      A1s[t] = a; C1s[t] = nq_b[t] - a*cm;
    }
    __syncthreads();
  }

  int m = l & 15, lq = l >> 4;

  // ---- A-fragments (xhat bf16), rows mt*16+m (clamped; garbage rows discarded)
  bf16x8 afr[2][4];
  #pragma unroll
  for(int mt = 0; mt < 2; ++mt){
    int row = mt*16 + m; if(row > GSIZE-1) row = GSIZE-1;
    const float* xr = x + (size_t)(base + row)*DIN;
    #pragma unroll
    for(int kk = 0; kk < 4; ++kk){
      int k0 = kk*32 + lq*8;
      float4 a = *(const float4*)(xr + k0);
      float4 b = *(const float4*)(xr + k0 + 4);
      U16B u;
      u.s[0] = f2bf(a.x*A1s[k0+0] + C1s[k0+0]);
      u.s[1] = f2bf(a.y*A1s[k0+1] + C1s[k0+1]);
      u.s[2] = f2bf(a.z*A1s[k0+2] + C1s[k0+2]);
      u.s[3] = f2bf(a.w*A1s[k0+3] + C1s[k0+3]);
      u.s[4] = f2bf(b.x*A1s[k0+4] + C1s[k0+4]);
      u.s[5] = f2bf(b.y*A1s[k0+5] + C1s[k0+5]);
      u.s[6] = f2bf(b.z*A1s[k0+6] + C1s[k0+6]);
      u.s[7] = f2bf(b.w*A1s[k0+7] + C1s[k0+7]);
      afr[mt][kk] = u.v;
    }
  }

  // ---- QKV GEMM per wave: head h's 192 out-cols (12 N-tiles of 16), to LDS
  #pragma unroll
  for(int nt = 0; nt < 12; ++nt){
    int mat = nt >> 2, sub = nt & 3;
    const unsigned short* wp = wcvt + (size_t)mat*EFF*DIN
                             + (size_t)(h*64 + sub*16 + m)*DIN + lq*8;
    const float* bias = (mat==0) ? bq : (mat==1) ? bk : bv;
    float4 bb = *(const float4*)(bias + h*64 + sub*16 + lq*4);
    f32x4 acc0 = {0.f,0.f,0.f,0.f}, acc1 = {0.f,0.f,0.f,0.f};
    #pragma unroll
    for(int kk = 0; kk < 4; ++kk){
      U16B w8; w8.u = *(const uint4*)(wp + kk*32);
      acc0 = __builtin_amdgcn_mfma_f32_16x16x32_bf16(w8.v, afr[0][kk], acc0, 0, 0, 0);
      acc1 = __builtin_amdgcn_mfma_f32_16x16x32_bf16(w8.v, afr[1][kk], acc1, 0, 0, 0);
    }
    float* dst = qlds + mat*(GSIZE*QSTRIDE);
    int col = h*64 + sub*16 + lq*4;
    {
      float4 o; o.x = acc0[0]+bb.x; o.y = acc0[1]+bb.y; o.z = acc0[2]+bb.z; o.w = acc0[3]+bb.w;
      *(float4*)(dst + m*QSTRIDE + col) = o;
    }
    if(m < 8){
      float4 o; o.x = acc1[0]+bb.x; o.y = acc1[1]+bb.y; o.z = acc1[2]+bb.z; o.w = acc1[3]+bb.w;
      *(float4*)(dst + (16+m)*QSTRIDE + col) = o;
    }
  }
  // NO barrier: wave h reads only its own columns from here on.

  // ---- S + softmax (3x3 register-blocked, wave-local; P overlays Q_h region)
  {
    int r0 = 3*(l >> 3), j0 = 3*(l & 7);
    const float* qp = qlds + r0*QSTRIDE + h*64;
    const float* kp = qlds + GSIZE*QSTRIDE + j0*QSTRIDE + h*64;
    float s00=0.f,s01=0.f,s02=0.f,s10=0.f,s11=0.f,s12=0.f,s20=0.f,s21=0.f,s22=0.f;
    #pragma unroll
    for(int d4 = 0; d4 < 16; ++d4){
      float4 q0 = *(const float4*)(qp + d4*4);
      float4 q1 = *(const float4*)(qp + QSTRIDE + d4*4);
      float4 q2 = *(const float4*)(qp + 2*QSTRIDE + d4*4);
      float4 k0 = *(const float4*)(kp + d4*4);
      float4 k1 = *(const float4*)(kp + QSTRIDE + d4*4);
      float4 k2 = *(const float4*)(kp + 2*QSTRIDE + d4*4);
      s00 += q0.x*k0.x + q0.y*k0.y + q0.z*k0.z + q0.w*k0.w;
      s01 += q0.x*k1.x + q0.y*k1.y + q0.z*k1.z + q0.w*k1.w;
      s02 += q0.x*k2.x + q0.y*k2.y + q0.z*k2.z + q0.w*k2.w;
      s10 += q1.x*k0.x + q1.y*k0.y + q1.z*k0.z + q1.w*k0.w;
      s11 += q1.x*k1.x + q1.y*k1.y + q1.z*k1.z + q1.w*k1.w;
      s12 += q1.x*k2.x + q1.y*k2.y + q1.z*k2.z + q1.w*k2.w;
      s20 += q2.x*k0.x + q2.y*k0.y + q2.z*k0.z + q2.w*k0.w;
      s21 += q2.x*k1.x + q2.y*k1.y + q2.z*k1.z + q2.w*k1.w;
      s22 += q2.x*k2.x + q2.y*k2.y + q2.z*k2.z + q2.w*k2.w;
    }
    float a0, a1, a2, m0, su, inv;
    float* STb = qlds + h*64;   // ST[j][r] at qlds[j*QSTRIDE + h*64 + r]
    a0 = s00*0.125f; a1 = s01*0.125f; a2 = s02*0.125f;
    m0 = fmaxf(fmaxf(a0, a1), a2);
    #pragma unroll
    for(int o = 1; o < 8; o <<= 1) m0 = fmaxf(m0, __shfl_xor(m0, o, 8));
    a0 = __expf(a0-m0); a1 = __expf(a1-m0); a2 = __expf(a2-m0);
    su = a0 + a1 + a2;
    #pragma unroll
    for(int o = 1; o < 8; o <<= 1) su += __shfl_xor(su, o, 8);
    inv = 1.0f/(su + 1e-16f);
    STb[(j0+0)*QSTRIDE + r0] = a0*inv; STb[(j0+1)*QSTRIDE + r0] = a1*inv; STb[(j0+2)*QSTRIDE + r0] = a2*inv;
    a0 = s10*0.125f; a1 = s11*0.125f; a2 = s12*0.125f;
    m0 = fmaxf(fmaxf(a0, a1), a2);
    #pragma unroll
    for(int o = 1; o < 8; o <<= 1) m0 = fmaxf(m0, __shfl_xor(m0, o, 8));
    a0 = __expf(a0-m0); a1 = __expf(a1-m0); a2 = __expf(a2-m0);
    su = a0 + a1 + a2;
    #pragma unroll
    for(int o = 1; o < 8; o <<= 1) su += __shfl_xor(su, o, 8);
    inv = 1.0f/(su + 1e-16f);
    STb[(j0+0)*QSTRIDE + r0+1] = a0*inv; STb[(j0+1)*QSTRIDE + r0+1] = a1*inv; STb[(j0+2)*QSTRIDE + r0+1] = a2*inv;
    a0 = s20*0.125f; a1 = s21*0.125f; a2 = s22*0.125f;
    m0 = fmaxf(fmaxf(a0, a1), a2);
    #pragma unroll
    for(int o = 1; o < 8; o <<= 1) m0 = fmaxf(m0, __shfl_xor(m0, o, 8));
    a0 = __expf(a0-m0); a1 = __expf(a1-m0); a2 = __expf(a2-m0);
    su = a0 + a1 + a2;
    #pragma unroll
    for(int o = 1; o < 8; o <<= 1) su += __shfl_xor(su, o, 8);
    inv = 1.0f/(su + 1e-16f);
    STb[(j0+0)*QSTRIDE + r0+2] = a0*inv; STb[(j0+1)*QSTRIDE + r0+2] = a1*inv; STb[(j0+2)*QSTRIDE + r0+2] = a2*inv;
  }

  // ---- PV: lane l = output dim d; V rows from LDS (2/bank, free); P broadcast
  {
    float o24[GSIZE];
    #pragma unroll
    for(int r = 0; r < GSIZE; ++r) o24[r] = 0.f;
    const float* vp  = qlds + 2*GSIZE*QSTRIDE + h*64 + l;
    const float* STb = qlds + h*64;
    #pragma unroll
    for(int j = 0; j < GSIZE; ++j){
      float v = vp[j*QSTRIDE];
      #pragma unroll
      for(int rq = 0; rq < 6; ++rq){
        float4 p4 = *(const float4*)(STb + j*QSTRIDE + rq*4);
        o24[rq*4+0] = fmaf(p4.x, v, o24[rq*4+0]);
        o24[rq*4+1] = fmaf(p4.y, v, o24[rq*4+1]);
        o24[rq*4+2] = fmaf(p4.z, v, o24[rq*4+2]);
        o24[rq*4+3] = fmaf(p4.w, v, o24[rq*4+3]);
      }
    }
    #pragma unroll
    for(int r = 0; r < GSIZE; ++r) atomicAdd(&hv[r][l], o24[r]);
  }
  __syncthreads();   // all heads accumulated

  // ---- combine: head mean + residual fold, write hcomb, rebuild hv
  #pragma unroll
  for(int sl = 0; sl < 3; ++sl){
    int idx = t + sl*512;
    int r = idx >> 6, d = idx & 63;
    const float* xr = x + (size_t)(base + r)*DIN;
    float hval = hv[r][d]*0.125f + xr[d] + xr[64 + d];
    hcomb[(size_t)(base + r)*DH + d] = hval;
    hv[r][d] = hval;
  }
  __syncthreads();
  if(t < 64){
    float s1 = 0.f, s2 = 0.f;
    #pragma unroll
    for(int i = 0; i < GSIZE; ++i){ float v = hv[i][t]; s1 += v; s2 += v*v; }
    ws[HP + g*128 + t]      = s1;
    ws[HP + g*128 + 64 + t] = s2;
  }
}

// ================= K3: k_final =================
// Folds k_hstats (redundant per-block A2/C2 reduce of L3-hot HP partials).
__global__ __launch_bounds__(256)
void k_final(const float* __restrict__ x,
             const float* __restrict__ hbuf, const float* __restrict__ ws,
             const float* __restrict__ no_w, const float* __restrict__ no_b,
             const float* __restrict__ no_ms,
             const float* __restrict__ pn_w, const float* __restrict__ pn_b,
             const float* __restrict__ pn_ms,
             float* __restrict__ out){
  __shared__ __align__(16) float W1[4096];
  __shared__ __align__(16) float W2[4096];
  __shared__ __align__(16) float PW1[4096];
  __shared__ __align__(16) float fbs[260];
  __shared__ __align__(16) float hs[GSIZE][68];
  __shared__ __align__(16) float hn[GSIZE][68];
  __shared__ __align__(16) float ts[GSIZE][68];
  __shared__ float A2s[DH], C2s[DH];
  __shared__ float a3[DH], c3[DH];
  __shared__ float scores[GSIZE], wsm[GSIZE];
  __shared__ float redA[256], redB[256];

  int t = threadIdx.x;
  int base = blockIdx.x * GSIZE;
  int c = t & 63, i0 = t >> 6;      // col + first row; rows i0+4r, r=0..5

  // ---- stage weights + fb (coalesced float4 burst) + HP reduce, same phase
  {
    const float4* s1 = (const float4*)(ws + WT1);
    const float4* s2 = (const float4*)(ws + WT2);
    const float4* s3 = (const float4*)(ws + PWT1);
    #pragma unroll
    for(int it = 0; it < 4; ++it){
      int i = t + it*256;
      ((float4*)W1)[i]  = s1[i];
      ((float4*)W2)[i]  = s2[i];
      ((float4*)PW1)[i] = s3[i];
    }
    if(t < 257) fbs[t] = ws[FBo + t];
    int cc = t & 63, grp = t >> 6;
    float s1r = 0.f, s2r = 0.f;
    for(int p = grp; p < NGRAPH; p += 4){
      s1r += ws[HP + p*128 + cc];
      s2r += ws[HP + p*128 + 64 + cc];
    }
    redA[t] = s1r; redB[t] = s2r;
  }
  __syncthreads();
  if(t < DH){
    float a1 = redA[t] + redA[t+64] + redA[t+128] + redA[t+192];
    float a2 = redB[t] + redB[t+64] + redB[t+128] + redB[t+192];
    float mean = a1 * (1.0f / N_NODES);
    float ex2  = a2 * (1.0f / N_NODES);
    float cm   = mean * no_ms[t];
    float var  = ex2 - 2.f*cm*mean + cm*cm;
    float rstd = rsqrtf(var + EPSN);
    float a    = no_w[t] * rstd;
    A2s[t] = a; C2s[t] = no_b[t] - a*cm;
  }
  __syncthreads();
  // ---- load h rows + apply global h-norm ----
  {
    float a2 = A2s[c];
    float c2 = C2s[c];
    #pragma unroll
    for(int r = 0; r < 6; ++r){
      int i = i0 + 4*r;
      float hvv = hbuf[(size_t)(base + i)*DH + c];
      hs[i][c] = hvv;
      hn[i][c] = a2*hvv + c2;
    }
  }
  __syncthreads();

  // ---- FF1: ts = gelu(hn @ W1 + b1), 6 rows/thread ----
  {
    float acc[6];
    #pragma unroll
    for(int r = 0; r < 6; ++r) acc[r] = fbs[c];
    #pragma unroll 16
    for(int k = 0; k < DH; ++k){
      float w = W1[k*DH + c];
      #pragma unroll
      for(int r = 0; r < 6; ++r) acc[r] = fmaf(hn[i0 + 4*r][k], w, acc[r]);
    }
    #pragma unroll
    for(int r = 0; r < 6; ++r) ts[i0 + 4*r][c] = gelu_exact(acc[r]);
  }
  __syncthreads();

  // ---- FF2: hs += ts @ W2 + b2 ----
  {
    float acc[6];
    #pragma unroll
    for(int r = 0; r < 6; ++r) acc[r] = fbs[64 + c];
    #pragma unroll 16
    for(int k = 0; k < DH; ++k){
      float w = W2[k*DH + c];
      #pragma unroll
      for(int r = 0; r < 6; ++r) acc[r] = fmaf(ts[i0 + 4*r][k], w, acc[r]);
    }
    #pragma unroll
    for(int r = 0; r < 6; ++r) hs[i0 + 4*r][c] += acc[r];
  }
  __syncthreads();

  // ---- per-graph pn-norm stats ----
  if(t < DH){
    float s1 = 0.f, s2 = 0.f;
    #pragma unroll
    for(int i = 0; i < GSIZE; i++){ float v = hs[i][t]; s1 += v; s2 += v*v; }
    float mean = s1 * (1.0f / GSIZE);
    float ex2  = s2 * (1.0f / GSIZE);
    float cm   = mean * pn_ms[t];
    float var  = ex2 - 2.f*cm*mean + cm*cm;
    float rstd = rsqrtf(var + EPSN);
    float a    = pn_w[t] * rstd;
    a3[t] = a; c3[t] = pn_b[t] - a*cm;
  }
  __syncthreads();

  // ---- PW1 MLP with pn-norm fused into operand ----
  {
    float acc[6];
    #pragma unroll
    for(int r = 0; r < 6; ++r) acc[r] = fbs[128 + c];
    #pragma unroll 16
    for(int k = 0; k < DH; ++k){
      float w  = PW1[k*DH + c];
      float ak = a3[k], ck = c3[k];
      #pragma unroll
      for(int r = 0; r < 6; ++r){
        float hnv = fmaf(ak, hs[i0 + 4*r][k], ck);
        acc[r] = fmaf(hnv, w, acc[r]);
      }
    }
    #pragma unroll
    for(int r = 0; r < 6; ++r) ts[i0 + 4*r][c] = gelu_exact(acc[r]);
  }
  __syncthreads();

  // ---- scores = ts @ p_w2 + pb2 ----
  if(t < GSIZE){
    const float4* tp = (const float4*)ts[t];
    const float4* wp = (const float4*)(fbs + 192);
    float s = fbs[256];
    #pragma unroll
    for(int q = 0; q < 16; ++q){
      float4 a = tp[q], b = wp[q];
      s += a.x*b.x + a.y*b.y + a.z*b.z + a.w*b.w;
    }
    scores[t] = s;
  }
  __syncthreads();
  if(t < GSIZE){
    float mx = -1e30f;
    #pragma unroll
    for(int j = 0; j < GSIZE; j++) mx = fmaxf(mx, scores[j]);
    float sum = 0.f;
    #pragma unroll
    for(int j = 0; j < GSIZE; j++) sum += __expf(scores[j] - mx);
    wsm[t] = __expf(scores[t] - mx) / (sum + 1e-16f);
  }
  __syncthreads();
  if(t < DIN){
    float s = 0.f;
    #pragma unroll 8
    for(int i = 0; i < GSIZE; i++) s += wsm[i] * x[(size_t)(base+i)*DIN + t];
    out[(size_t)blockIdx.x*DIN + t] = s;
  }
}

extern "C" void kernel_launch(void* const* d_in, const int* in_sizes, int n_in,
                              void* d_out, int out_size, void* d_ws, size_t ws_size,
                              hipStream_t stream){
  (void)in_sizes; (void)n_in; (void)out_size; (void)ws_size;
  const float* x    = (const float*)d_in[0];
  const float* nq_w = (const float*)d_in[4];
  const float* nq_b = (const float*)d_in[5];
  const float* nq_ms= (const float*)d_in[6];
  const float* wq   = (const float*)d_in[7];
  const float* bq   = (const float*)d_in[8];
  const float* wk   = (const float*)d_in[9];
  const float* bk   = (const float*)d_in[10];
  const float* wv   = (const float*)d_in[11];
  const float* bv   = (const float*)d_in[12];
  const float* no_w = (const float*)d_in[13];
  const float* no_b = (const float*)d_in[14];
  const float* no_ms= (const float*)d_in[15];
  const float* o_w1 = (const float*)d_in[16];
  const float* o_b1 = (const float*)d_in[17];
  const float* o_w2 = (const float*)d_in[18];
  const float* o_b2 = (const float*)d_in[19];
  const float* pn_w = (const float*)d_in[20];
  const float* pn_b = (const float*)d_in[21];
  const float* pn_ms= (const float*)d_in[22];
  const float* p_w1 = (const float*)d_in[23];
  const float* p_b1 = (const float*)d_in[24];
  const float* p_w2 = (const float*)d_in[25];
  const float* p_b2 = (const float*)d_in[26];

  float* ws    = (float*)d_ws;
  float* hcomb = (float*)((char*)d_ws + HCOMB_BYTE);

  k_pre<<<207, 256, 0, stream>>>(x, o_w1, o_w2, p_w1, o_b1, o_b2, p_b1, p_w2, p_b2,
                                 wq, wk, wv, ws);
  k_attn2<<<NGRAPH, 512, 0, stream>>>(x, bq, bk, bv, nq_w, nq_b, nq_ms, ws, hcomb);
  k_final<<<NGRAPH, 256, 0, stream>>>(x, hcomb, ws, no_w, no_b, no_ms,
                                      pn_w, pn_b, pn_ms, (float*)d_out);
}

// Round 4
// 171.167 us; speedup vs baseline: 1.1824x; 1.0576x over previous
//
#include <hip/hip_runtime.h>
#include <stdint.h>

// FP32 in/out. bf16 only for MFMA operands.
// R17: kill redundant per-block stat reduces (96 ld/thr in k_attn2, 128 ld/thr
// in k_final -- the dominant exposed-latency phases at 1 block/CU) via
// device atomicAdd accumulation in k_pre/k_attn2 tails; consumers load 2
// floats/thread. Adds hipMemsetAsync(1.5KB) zero node. QKV weight stream now
// depth-2 prefetched (3-buffer static rotation; R8's spill was union arrays).
// NOTE: atomic sum reorder perturbs norm stats ~1e-7 rel; if absmax jumps,
// revert atomics first.
// Ledger: R16 fuse qkv+attn, LDS-resident QKV (195.6->181.0; k_attn2 45us,
// 85% stall); R15 k_final LDS-staged MLP (49.7-><45); R14 split k_fused;
// R6 mega-kernel +150us; R8 union prefetch spills; R10 launch_bounds spill.

#define N_NODES 6144
#define GSIZE 24
#define NGRAPH 256
#define DIN 128
#define DH 64
#define EFF 512
#define EPSN 1e-5f

typedef __attribute__((ext_vector_type(8))) __bf16 bf16x8;
typedef __attribute__((ext_vector_type(4))) float f32x4;
union U16B { uint4 u; bf16x8 v; unsigned short s[8]; };

__device__ inline unsigned short f2bf(float f){
  unsigned u = __float_as_uint(f);
  u += 0x7fff + ((u>>16)&1);
  return (unsigned short)(u>>16);
}
__device__ inline float gelu_exact(float x){ return 0.5f*x*(1.0f+erff(x*0.70710678118654752f)); }

// ---- workspace float offsets ----
#define XS    0         // 256 floats: x col sum (128) + sumsq (128), ATOMIC
#define HS    256       // 128 floats: h col sum (64) + sumsq (64), ATOMIC
#define WT1   81920
#define WT2   86016
#define PWT1  90112
#define FBo   94208     // 257 floats
#define WCVT_BYTE  385024   // 3 x 512 x 128 bf16 = 393216 B
#define HCOMB_BYTE 778240   // 6144 x 64 fp32

#define QSTRIDE 516     // fp32 row stride for LDS QKV (padded)

// ================= K1: k_pre =================
// blocks 0..191: x col-stat partials -> ATOMIC add into XS
// blocks 192..194: transpose o_w1/o_w2/p_w1 (+bias staging in 192)
// blocks 195..206: wq/wk/wv -> bf16 (12 segments)
__global__ __launch_bounds__(256)
void k_pre(const float* __restrict__ x,
           const float* __restrict__ o_w1, const float* __restrict__ o_w2,
           const float* __restrict__ p_w1,
           const float* __restrict__ o_b1, const float* __restrict__ o_b2,
           const float* __restrict__ p_b1, const float* __restrict__ p_w2,
           const float* __restrict__ p_b2,
           const float* __restrict__ wq, const float* __restrict__ wk,
           const float* __restrict__ wv,
           float* __restrict__ wsf){
  int t = threadIdx.x;
  int bi = blockIdx.x;
  if(bi < 192){
    int c = t & 127, h = t >> 7;
    float s = 0.f, q = 0.f;
    #pragma unroll
    for(int r = 0; r < 16; ++r){
      float v = x[(size_t)(bi*32 + h + 2*r)*DIN + c];
      s += v; q += v*v;
    }
    __shared__ float sm[256], sm2[256];
    sm[t] = s; sm2[t] = q;
    __syncthreads();
    if(t < 128){
      atomicAdd(&wsf[XS + t],       sm[t] + sm[t+128]);
      atomicAdd(&wsf[XS + 128 + t], sm2[t] + sm2[t+128]);
    }
    return;
  }
  if(bi < 195){
    const float* src; float* dst;
    if(bi == 192){ src = o_w1; dst = wsf + WT1; }
    else if(bi == 193){ src = o_w2; dst = wsf + WT2; }
    else { src = p_w1; dst = wsf + PWT1; }
    for(int p = t; p < DH*DH; p += 256){
      int r = p >> 6, c = p & 63;
      dst[c*DH + r] = src[p];
    }
    if(bi == 192){
      float* fb = wsf + FBo;
      if(t < 64){
        fb[t]       = o_b1[t];
        fb[64 + t]  = o_b2[t];
        fb[128 + t] = p_b1[t];
        fb[192 + t] = p_w2[t];
      }
      if(t == 0) fb[256] = p_b2[0];
    }
    return;
  }
  int j = bi - 195;               // 0..11
  int mat = j >> 2, seg = j & 3;
  const float* src = (mat==0) ? wq : (mat==1) ? wk : wv;
  unsigned short* dst = (unsigned short*)((char*)wsf + WCVT_BYTE)
                        + (size_t)mat*EFF*DIN + seg*16384;
  const float* sp = src + seg*16384;
  for(int e = t*8; e < 16384; e += 2048){
    float4 a = *(const float4*)(sp + e);
    float4 b = *(const float4*)(sp + e + 4);
    U16B o;
    o.s[0]=f2bf(a.x); o.s[1]=f2bf(a.y); o.s[2]=f2bf(a.z); o.s[3]=f2bf(a.w);
    o.s[4]=f2bf(b.x); o.s[5]=f2bf(b.y); o.s[6]=f2bf(b.z); o.s[7]=f2bf(b.w);
    *(uint4*)(dst + e) = o.u;
  }
}

// ---- QKV weight tile load/compute macros (static buffers; depth-2 pipeline)
#define LOADW(nt, W, B) do{ \
  const int mat_ = (nt)>>2, sub_ = (nt)&3; \
  const unsigned short* wp_ = wcvt + (size_t)mat_*EFF*DIN \
      + (size_t)(h*64 + sub_*16 + m)*DIN + lq*8; \
  W[0] = *(const uint4*)(wp_);      W[1] = *(const uint4*)(wp_ + 32); \
  W[2] = *(const uint4*)(wp_ + 64); W[3] = *(const uint4*)(wp_ + 96); \
  const float* bias_ = (mat_==0) ? bq : (mat_==1) ? bk : bv; \
  B = *(const float4*)(bias_ + h*64 + sub_*16 + lq*4); \
}while(0)

#define COMPW(nt, W, B) do{ \
  const int mat_ = (nt)>>2, sub_ = (nt)&3; \
  f32x4 a0_ = {0.f,0.f,0.f,0.f}, a1_ = {0.f,0.f,0.f,0.f}; \
  U16B w8_; \
  w8_.u = W[0]; \
  a0_ = __builtin_amdgcn_mfma_f32_16x16x32_bf16(w8_.v, afr[0][0], a0_, 0, 0, 0); \
  a1_ = __builtin_amdgcn_mfma_f32_16x16x32_bf16(w8_.v, afr[1][0], a1_, 0, 0, 0); \
  w8_.u = W[1]; \
  a0_ = __builtin_amdgcn_mfma_f32_16x16x32_bf16(w8_.v, afr[0][1], a0_, 0, 0, 0); \
  a1_ = __builtin_amdgcn_mfma_f32_16x16x32_bf16(w8_.v, afr[1][1], a1_, 0, 0, 0); \
  w8_.u = W[2]; \
  a0_ = __builtin_amdgcn_mfma_f32_16x16x32_bf16(w8_.v, afr[0][2], a0_, 0, 0, 0); \
  a1_ = __builtin_amdgcn_mfma_f32_16x16x32_bf16(w8_.v, afr[1][2], a1_, 0, 0, 0); \
  w8_.u = W[3]; \
  a0_ = __builtin_amdgcn_mfma_f32_16x16x32_bf16(w8_.v, afr[0][3], a0_, 0, 0, 0); \
  a1_ = __builtin_amdgcn_mfma_f32_16x16x32_bf16(w8_.v, afr[1][3], a1_, 0, 0, 0); \
  float* dst_ = qlds + mat_*(GSIZE*QSTRIDE); \
  const int col_ = h*64 + sub_*16 + lq*4; \
  { float4 o_; o_.x=a0_[0]+B.x; o_.y=a0_[1]+B.y; o_.z=a0_[2]+B.z; o_.w=a0_[3]+B.w; \
    *(float4*)(dst_ + m*QSTRIDE + col_) = o_; } \
  if(m < 8){ float4 o_; o_.x=a1_[0]+B.x; o_.y=a1_[1]+B.y; o_.z=a1_[2]+B.z; o_.w=a1_[3]+B.w; \
    *(float4*)(dst_ + (16+m)*QSTRIDE + col_) = o_; } \
}while(0)

// ================= K2: k_attn2 =================
// Block = 1 graph (24 nodes), 512 thr = 8 waves = 8 heads.
// LDS: QKV fp32 [3][24][516] (148.6KB) + hv (6.5KB) + A1s/C1s (1KB) = 156KB.
// Stats loaded directly from XS (2 ld/thread); QKV weights depth-2 prefetched;
// h-stats emitted via atomicAdd to HS. 3 barriers total.
__global__ __launch_bounds__(512)
void k_attn2(const float* __restrict__ x,
             const float* __restrict__ bq, const float* __restrict__ bk,
             const float* __restrict__ bv,
             const float* __restrict__ nq_w, const float* __restrict__ nq_b,
             const float* __restrict__ nq_ms,
             float* __restrict__ ws, float* __restrict__ hcomb){
  __shared__ __align__(16) float qlds[3*GSIZE*QSTRIDE];  // 148,608 B
  __shared__ __align__(16) float hv[GSIZE][68];          // 6,528 B
  __shared__ float A1s[DIN], C1s[DIN];                   // 1,024 B

  int t = threadIdx.x, g = blockIdx.x, base = g*GSIZE;
  int h = t >> 6, l = t & 63;
  const unsigned short* wcvt = (const unsigned short*)((const char*)ws + WCVT_BYTE);

  for(int i = t; i < GSIZE*68; i += 512) ((float*)hv)[i] = 0.f;

  // ---- x-norm coeffs from atomic sums (2 loads/thread)
  if(t < 128){
    float s1 = ws[XS + t];
    float q1 = ws[XS + 128 + t];
    float mean = s1 * (1.0f / N_NODES);
    float ex2  = q1 * (1.0f / N_NODES);
    float cm   = mean * nq_ms[t];
    float var  = ex2 - 2.f*cm*mean + cm*cm;
    float rstd = rsqrtf(var + EPSN);
    float a    = nq_w[t] * rstd;
    A1s[t] = a; C1s[t] = nq_b[t] - a*cm;
  }
  __syncthreads();

  int m = l & 15, lq = l >> 4;

  // ---- A-fragments (xhat bf16), rows mt*16+m (clamped; garbage rows discarded)
  bf16x8 afr[2][4];
  #pragma unroll
  for(int mt = 0; mt < 2; ++mt){
    int row = mt*16 + m; if(row > GSIZE-1) row = GSIZE-1;
    const float* xr = x + (size_t)(base + row)*DIN;
    #pragma unroll
    for(int kk = 0; kk < 4; ++kk){
      int k0 = kk*32 + lq*8;
      float4 a = *(const float4*)(xr + k0);
      float4 b = *(const float4*)(xr + k0 + 4);
      U16B u;
      u.s[0] = f2bf(a.x*A1s[k0+0] + C1s[k0+0]);
      u.s[1] = f2bf(a.y*A1s[k0+1] + C1s[k0+1]);
      u.s[2] = f2bf(a.z*A1s[k0+2] + C1s[k0+2]);
      u.s[3] = f2bf(a.w*A1s[k0+3] + C1s[k0+3]);
      u.s[4] = f2bf(b.x*A1s[k0+4] + C1s[k0+4]);
      u.s[5] = f2bf(b.y*A1s[k0+5] + C1s[k0+5]);
      u.s[6] = f2bf(b.z*A1s[k0+6] + C1s[k0+6]);
      u.s[7] = f2bf(b.w*A1s[k0+7] + C1s[k0+7]);
      afr[mt][kk] = u.v;
    }
  }

  // ---- QKV GEMM per wave: head h's 192 out-cols, depth-2 prefetch pipeline
  {
    uint4 wA[4], wB[4], wC[4];
    float4 bA, bB, bC;
    LOADW(0, wA, bA);  LOADW(1, wB, bB);
    LOADW(2, wC, bC);  COMPW(0, wA, bA);
    LOADW(3, wA, bA);  COMPW(1, wB, bB);
    LOADW(4, wB, bB);  COMPW(2, wC, bC);
    LOADW(5, wC, bC);  COMPW(3, wA, bA);
    LOADW(6, wA, bA);  COMPW(4, wB, bB);
    LOADW(7, wB, bB);  COMPW(5, wC, bC);
    LOADW(8, wC, bC);  COMPW(6, wA, bA);
    LOADW(9, wA, bA);  COMPW(7, wB, bB);
    LOADW(10, wB, bB); COMPW(8, wC, bC);
    LOADW(11, wC, bC); COMPW(9, wA, bA);
    COMPW(10, wB, bB);
    COMPW(11, wC, bC);
  }
  // NO barrier: wave h reads only its own columns from here on.

  // ---- S + softmax (3x3 register-blocked, wave-local; P overlays Q_h region)
  {
    int r0 = 3*(l >> 3), j0 = 3*(l & 7);
    const float* qp = qlds + r0*QSTRIDE + h*64;
    const float* kp = qlds + GSIZE*QSTRIDE + j0*QSTRIDE + h*64;
    float s00=0.f,s01=0.f,s02=0.f,s10=0.f,s11=0.f,s12=0.f,s20=0.f,s21=0.f,s22=0.f;
    #pragma unroll
    for(int d4 = 0; d4 < 16; ++d4){
      float4 q0 = *(const float4*)(qp + d4*4);
      float4 q1 = *(const float4*)(qp + QSTRIDE + d4*4);
      float4 q2 = *(const float4*)(qp + 2*QSTRIDE + d4*4);
      float4 k0 = *(const float4*)(kp + d4*4);
      float4 k1 = *(const float4*)(kp + QSTRIDE + d4*4);
      float4 k2 = *(const float4*)(kp + 2*QSTRIDE + d4*4);
      s00 += q0.x*k0.x + q0.y*k0.y + q0.z*k0.z + q0.w*k0.w;
      s01 += q0.x*k1.x + q0.y*k1.y + q0.z*k1.z + q0.w*k1.w;
      s02 += q0.x*k2.x + q0.y*k2.y + q0.z*k2.z + q0.w*k2.w;
      s10 += q1.x*k0.x + q1.y*k0.y + q1.z*k0.z + q1.w*k0.w;
      s11 += q1.x*k1.x + q1.y*k1.y + q1.z*k1.z + q1.w*k1.w;
      s12 += q1.x*k2.x + q1.y*k2.y + q1.z*k2.z + q1.w*k2.w;
      s20 += q2.x*k0.x + q2.y*k0.y + q2.z*k0.z + q2.w*k0.w;
      s21 += q2.x*k1.x + q2.y*k1.y + q2.z*k1.z + q2.w*k1.w;
      s22 += q2.x*k2.x + q2.y*k2.y + q2.z*k2.z + q2.w*k2.w;
    }
    float a0, a1, a2, m0, su, inv;
    float* STb = qlds + h*64;   // ST[j][r] at qlds[j*QSTRIDE + h*64 + r]
    a0 = s00*0.125f; a1 = s01*0.125f; a2 = s02*0.125f;
    m0 = fmaxf(fmaxf(a0, a1), a2);
    #pragma unroll
    for(int o = 1; o < 8; o <<= 1) m0 = fmaxf(m0, __shfl_xor(m0, o, 8));
    a0 = __expf(a0-m0); a1 = __expf(a1-m0); a2 = __expf(a2-m0);
    su = a0 + a1 + a2;
    #pragma unroll
    for(int o = 1; o < 8; o <<= 1) su += __shfl_xor(su, o, 8);
    inv = 1.0f/(su + 1e-16f);
    STb[(j0+0)*QSTRIDE + r0] = a0*inv; STb[(j0+1)*QSTRIDE + r0] = a1*inv; STb[(j0+2)*QSTRIDE + r0] = a2*inv;
    a0 = s10*0.125f; a1 = s11*0.125f; a2 = s12*0.125f;
    m0 = fmaxf(fmaxf(a0, a1), a2);
    #pragma unroll
    for(int o = 1; o < 8; o <<= 1) m0 = fmaxf(m0, __shfl_xor(m0, o, 8));
    a0 = __expf(a0-m0); a1 = __expf(a1-m0); a2 = __expf(a2-m0);
    su = a0 + a1 + a2;
    #pragma unroll
    for(int o = 1; o < 8; o <<= 1) su += __shfl_xor(su, o, 8);
    inv = 1.0f/(su + 1e-16f);
    STb[(j0+0)*QSTRIDE + r0+1] = a0*inv; STb[(j0+1)*QSTRIDE + r0+1] = a1*inv; STb[(j0+2)*QSTRIDE + r0+1] = a2*inv;
    a0 = s20*0.125f; a1 = s21*0.125f; a2 = s22*0.125f;
    m0 = fmaxf(fmaxf(a0, a1), a2);
    #pragma unroll
    for(int o = 1; o < 8; o <<= 1) m0 = fmaxf(m0, __shfl_xor(m0, o, 8));
    a0 = __expf(a0-m0); a1 = __expf(a1-m0); a2 = __expf(a2-m0);
    su = a0 + a1 + a2;
    #pragma unroll
    for(int o = 1; o < 8; o <<= 1) su += __shfl_xor(su, o, 8);
    inv = 1.0f/(su + 1e-16f);
    STb[(j0+0)*QSTRIDE + r0+2] = a0*inv; STb[(j0+1)*QSTRIDE + r0+2] = a1*inv; STb[(j0+2)*QSTRIDE + r0+2] = a2*inv;
  }

  // ---- PV: lane l = output dim d; V rows from LDS; P broadcast
  {
    float o24[GSIZE];
    #pragma unroll
    for(int r = 0; r < GSIZE; ++r) o24[r] = 0.f;
    const float* vp  = qlds + 2*GSIZE*QSTRIDE + h*64 + l;
    const float* STb = qlds + h*64;
    #pragma unroll
    for(int j = 0; j < GSIZE; ++j){
      float v = vp[j*QSTRIDE];
      #pragma unroll
      for(int rq = 0; rq < 6; ++rq){
        float4 p4 = *(const float4*)(STb + j*QSTRIDE + rq*4);
        o24[rq*4+0] = fmaf(p4.x, v, o24[rq*4+0]);
        o24[rq*4+1] = fmaf(p4.y, v, o24[rq*4+1]);
        o24[rq*4+2] = fmaf(p4.z, v, o24[rq*4+2]);
        o24[rq*4+3] = fmaf(p4.w, v, o24[rq*4+3]);
      }
    }
    #pragma unroll
    for(int r = 0; r < GSIZE; ++r) atomicAdd(&hv[r][l], o24[r]);
  }
  __syncthreads();   // all heads accumulated

  // ---- combine: head mean + residual fold, write hcomb, rebuild hv
  #pragma unroll
  for(int sl = 0; sl < 3; ++sl){
    int idx = t + sl*512;
    int r = idx >> 6, d = idx & 63;
    const float* xr = x + (size_t)(base + r)*DIN;
    float hval = hv[r][d]*0.125f + xr[d] + xr[64 + d];
    hcomb[(size_t)(base + r)*DH + d] = hval;
    hv[r][d] = hval;
  }
  __syncthreads();
  if(t < 64){
    float s1 = 0.f, s2 = 0.f;
    #pragma unroll
    for(int i = 0; i < GSIZE; ++i){ float v = hv[i][t]; s1 += v; s2 += v*v; }
    atomicAdd(&ws[HS + t],      s1);
    atomicAdd(&ws[HS + 64 + t], s2);
  }
}

// ================= K3: k_final =================
// A2/C2 from atomic HS sums (2 ld/thread); weights LDS-staged; 6-row
// register-blocked MLPs; pn-norm fused into PW1 operand.
__global__ __launch_bounds__(256)
void k_final(const float* __restrict__ x,
             const float* __restrict__ hbuf, const float* __restrict__ ws,
             const float* __restrict__ no_w, const float* __restrict__ no_b,
             const float* __restrict__ no_ms,
             const float* __restrict__ pn_w, const float* __restrict__ pn_b,
             const float* __restrict__ pn_ms,
             float* __restrict__ out){
  __shared__ __align__(16) float W1[4096];
  __shared__ __align__(16) float W2[4096];
  __shared__ __align__(16) float PW1[4096];
  __shared__ __align__(16) float fbs[260];
  __shared__ __align__(16) float hs[GSIZE][68];
  __shared__ __align__(16) float hn[GSIZE][68];
  __shared__ __align__(16) float ts[GSIZE][68];
  __shared__ float A2s[DH], C2s[DH];
  __shared__ float a3[DH], c3[DH];
  __shared__ float scores[GSIZE], wsm[GSIZE];

  int t = threadIdx.x;
  int base = blockIdx.x * GSIZE;
  int c = t & 63, i0 = t >> 6;      // col + first row; rows i0+4r, r=0..5

  // ---- stage weights + fb + h-norm coeffs (one phase) ----
  {
    const float4* s1 = (const float4*)(ws + WT1);
    const float4* s2 = (const float4*)(ws + WT2);
    const float4* s3 = (const float4*)(ws + PWT1);
    #pragma unroll
    for(int it = 0; it < 4; ++it){
      int i = t + it*256;
      ((float4*)W1)[i]  = s1[i];
      ((float4*)W2)[i]  = s2[i];
      ((float4*)PW1)[i] = s3[i];
    }
    if(t < 257) fbs[t] = ws[FBo + t];
    if(t < DH){
      float a1 = ws[HS + t];
      float a2 = ws[HS + 64 + t];
      float mean = a1 * (1.0f / N_NODES);
      float ex2  = a2 * (1.0f / N_NODES);
      float cm   = mean * no_ms[t];
      float var  = ex2 - 2.f*cm*mean + cm*cm;
      float rstd = rsqrtf(var + EPSN);
      float a    = no_w[t] * rstd;
      A2s[t] = a; C2s[t] = no_b[t] - a*cm;
    }
  }
  __syncthreads();
  // ---- load h rows + apply global h-norm ----
  {
    float a2 = A2s[c];
    float c2 = C2s[c];
    #pragma unroll
    for(int r = 0; r < 6; ++r){
      int i = i0 + 4*r;
      float hvv = hbuf[(size_t)(base + i)*DH + c];
      hs[i][c] = hvv;
      hn[i][c] = a2*hvv + c2;
    }
  }
  __syncthreads();

  // ---- FF1: ts = gelu(hn @ W1 + b1), 6 rows/thread ----
  {
    float acc[6];
    #pragma unroll
    for(int r = 0; r < 6; ++r) acc[r] = fbs[c];
    #pragma unroll 16
    for(int k = 0; k < DH; ++k){
      float w = W1[k*DH + c];
      #pragma unroll
      for(int r = 0; r < 6; ++r) acc[r] = fmaf(hn[i0 + 4*r][k], w, acc[r]);
    }
    #pragma unroll
    for(int r = 0; r < 6; ++r) ts[i0 + 4*r][c] = gelu_exact(acc[r]);
  }
  __syncthreads();

  // ---- FF2: hs += ts @ W2 + b2 ----
  {
    float acc[6];
    #pragma unroll
    for(int r = 0; r < 6; ++r) acc[r] = fbs[64 + c];
    #pragma unroll 16
    for(int k = 0; k < DH; ++k){
      float w = W2[k*DH + c];
      #pragma unroll
      for(int r = 0; r < 6; ++r) acc[r] = fmaf(ts[i0 + 4*r][k], w, acc[r]);
    }
    #pragma unroll
    for(int r = 0; r < 6; ++r) hs[i0 + 4*r][c] += acc[r];
  }
  __syncthreads();

  // ---- per-graph pn-norm stats ----
  if(t < DH){
    float s1 = 0.f, s2 = 0.f;
    #pragma unroll
    for(int i = 0; i < GSIZE; i++){ float v = hs[i][t]; s1 += v; s2 += v*v; }
    float mean = s1 * (1.0f / GSIZE);
    float ex2  = s2 * (1.0f / GSIZE);
    float cm   = mean * pn_ms[t];
    float var  = ex2 - 2.f*cm*mean + cm*cm;
    float rstd = rsqrtf(var + EPSN);
    float a    = pn_w[t] * rstd;
    a3[t] = a; c3[t] = pn_b[t] - a*cm;
  }
  __syncthreads();

  // ---- PW1 MLP with pn-norm fused into operand ----
  {
    float acc[6];
    #pragma unroll
    for(int r = 0; r < 6; ++r) acc[r] = fbs[128 + c];
    #pragma unroll 16
    for(int k = 0; k < DH; ++k){
      float w  = PW1[k*DH + c];
      float ak = a3[k], ck = c3[k];
      #pragma unroll
      for(int r = 0; r < 6; ++r){
        float hnv = fmaf(ak, hs[i0 + 4*r][k], ck);
        acc[r] = fmaf(hnv, w, acc[r]);
      }
    }
    #pragma unroll
    for(int r = 0; r < 6; ++r) ts[i0 + 4*r][c] = gelu_exact(acc[r]);
  }
  __syncthreads();

  // ---- scores = ts @ p_w2 + pb2 ----
  if(t < GSIZE){
    const float4* tp = (const float4*)ts[t];
    const float4* wp = (const float4*)(fbs + 192);
    float s = fbs[256];
    #pragma unroll
    for(int q = 0; q < 16; ++q){
      float4 a = tp[q], b = wp[q];
      s += a.x*b.x + a.y*b.y + a.z*b.z + a.w*b.w;
    }
    scores[t] = s;
  }
  __syncthreads();
  if(t < GSIZE){
    float mx = -1e30f;
    #pragma unroll
    for(int j = 0; j < GSIZE; j++) mx = fmaxf(mx, scores[j]);
    float sum = 0.f;
    #pragma unroll
    for(int j = 0; j < GSIZE; j++) sum += __expf(scores[j] - mx);
    wsm[t] = __expf(scores[t] - mx) / (sum + 1e-16f);
  }
  __syncthreads();
  if(t < DIN){
    float s = 0.f;
    #pragma unroll 8
    for(int i = 0; i < GSIZE; i++) s += wsm[i] * x[(size_t)(base+i)*DIN + t];
    out[(size_t)blockIdx.x*DIN + t] = s;
  }
}

extern "C" void kernel_launch(void* const* d_in, const int* in_sizes, int n_in,
                              void* d_out, int out_size, void* d_ws, size_t ws_size,
                              hipStream_t stream){
  (void)in_sizes; (void)n_in; (void)out_size; (void)ws_size;
  const float* x    = (const float*)d_in[0];
  const float* nq_w = (const float*)d_in[4];
  const float* nq_b = (const float*)d_in[5];
  const float* nq_ms= (const float*)d_in[6];
  const float* wq   = (const float*)d_in[7];
  const float* bq   = (const float*)d_in[8];
  const float* wk   = (const float*)d_in[9];
  const float* bk   = (const float*)d_in[10];
  const float* wv   = (const float*)d_in[11];
  const float* bv   = (const float*)d_in[12];
  const float* no_w = (const float*)d_in[13];
  const float* no_b = (const float*)d_in[14];
  const float* no_ms= (const float*)d_in[15];
  const float* o_w1 = (const float*)d_in[16];
  const float* o_b1 = (const float*)d_in[17];
  const float* o_w2 = (const float*)d_in[18];
  const float* o_b2 = (const float*)d_in[19];
  const float* pn_w = (const float*)d_in[20];
  const float* pn_b = (const float*)d_in[21];
  const float* pn_ms= (const float*)d_in[22];
  const float* p_w1 = (const float*)d_in[23];
  const float* p_b1 = (const float*)d_in[24];
  const float* p_w2 = (const float*)d_in[25];
  const float* p_b2 = (const float*)d_in[26];

  float* ws    = (float*)d_ws;
  float* hcomb = (float*)((char*)d_ws + HCOMB_BYTE);

  // zero the atomic accumulators (XS 256 + HS 128 floats; ws is poisoned)
  hipMemsetAsync(d_ws, 0, 384*sizeof(float), stream);
  k_pre<<<207, 256, 0, stream>>>(x, o_w1, o_w2, p_w1, o_b1, o_b2, p_b1, p_w2, p_b2,
                                 wq, wk, wv, ws);
  k_attn2<<<NGRAPH, 512, 0, stream>>>(x, bq, bk, bv, nq_w, nq_b, nq_ms, ws, hcomb);
  k_final<<<NGRAPH, 256, 0, stream>>>(x, hcomb, ws, no_w, no_b, no_ms,
                                      pn_w, pn_b, pn_ms, (float*)d_out);
}